// Round 10
// baseline (909.995 us; speedup 1.0000x reference)
//
#include <hip/hip_runtime.h>
#include <math.h>

#define NBATCH 4096
#define TNUM   128
#define NOBSC  10
#define MAXIT  30

// ws layout (floats)
#define WS_MX   0      // 16x16
#define WS_MY   256    // 16x16
#define WS_MGX  512    // 16x16  (Mx*Gx)
#define WS_MGY  768    // 16x16  (My*Gy)
#define WS_NX   1024   // 16x8
#define WS_NY   1152   // 16x9
#define WS_NX0  1296   // 16x8
#define WS_NY0  1424   // 16x9
// total 1568 floats

#define RS 36          // red row stride (16 quad-rows x 32 cols + pad)

typedef float f32x2 __attribute__((ext_vector_type(2)));
union F4 { float4 v; float f[4]; };

__device__ __forceinline__ f32x2 pfma(f32x2 a, f32x2 b, f32x2 c) {
  return __builtin_elementwise_fma(a, b, c);
}

// quad-lane (4 consecutive lanes) all-reduce sum via DPP (VALU pipe, no LDS)
__device__ __forceinline__ float qsum(float v) {
  float s = v + __int_as_float(__builtin_amdgcn_update_dpp(
      0, __float_as_int(v), 0xB1, 0xF, 0xF, true));   // quad_perm [1,0,3,2] = xor1
  s = s + __int_as_float(__builtin_amdgcn_update_dpp(
      0, __float_as_int(s), 0x4E, 0xF, 0xF, true));   // quad_perm [2,3,0,1] = xor2
  return s;
}

// ---------------- setup kernel: build + invert KKT matrices (fp64 GJ) -------
__global__ __launch_bounds__(64) void planner_setup(
    const float* __restrict__ P, const float* __restrict__ Pd, const float* __restrict__ Pdd,
    float* __restrict__ ws)
{
  const int mid = blockIdx.x;   // 0: (cost_sm,Ax)->Nx0  1: (cost_sm,Ay)->Ny0
                                // 2: (cost_x,Ax)->Mx,Nx,MGx 3: (cost_y,Ay)->My,Ny,MGy
  const int tid = threadIdx.x;
  __shared__ double C[16][16];
  __shared__ double G[16][16];
  __shared__ double Ae[9][16];
  __shared__ double aug[25][50];
  __shared__ int pivs;

  const bool isY = (mid & 1);
  const int  m   = isY ? 9 : 8;
  const int  n   = 16 + m;
  const int  w   = 2 * n;

  for (int e = tid; e < 256; e += 64) {
    const int j = e >> 4, kk = e & 15;
    double gdd = 0.0, gd = 0.0, g0 = 0.0;
    for (int t = 0; t < TNUM; ++t) {
      gdd += (double)Pdd[t*16+j] * (double)Pdd[t*16+kk];
      gd  += (double)Pd [t*16+j] * (double)Pd [t*16+kk];
      g0  += (double)P  [t*16+j] * (double)P  [t*16+kk];
    }
    const double cs = 100.0 * (gdd + ((j == kk) ? 0.1 : 0.0));
    const double g  = gdd + gd + (isY ? 12.0 : 10.0) * g0;
    G[j][kk] = g;
    C[j][kk] = (mid >= 2) ? (cs + g) : cs;
  }
  if (tid < 16) {
    const int j = tid;
    Ae[0][j] = (double)P  [0*16+j];
    Ae[1][j] = (double)Pd [0*16+j];
    Ae[2][j] = (double)Pdd[0*16+j];
    if (!isY) {
      Ae[3][j] = (double)Pd[127*16+j];
      for (int r = 4; r < 8; ++r) Ae[r][j] = (j == r) ? 1.0 : 0.0;
    } else {
      Ae[3][j] = (double)P [127*16+j];
      Ae[4][j] = (double)Pd[127*16+j];
      for (int r = 5; r < 9; ++r) Ae[r][j] = (j == (r-1)) ? 1.0 : 0.0;
    }
  }
  __syncthreads();

  for (int e = tid; e < n * w; e += 64) {
    const int r = e / w, c = e % w;
    double val;
    if (c < n) {
      if (r < 16) val = (c < 16) ? C[r][c] : Ae[c-16][r];
      else        val = (c < 16) ? Ae[r-16][c] : 0.0;
    } else {
      val = ((c - n) == r) ? 1.0 : 0.0;
    }
    aug[r][c] = val;
  }
  __syncthreads();

  for (int kk = 0; kk < n; ++kk) {
    if (tid == 0) {
      int p = kk; double best = fabs(aug[kk][kk]);
      for (int r = kk+1; r < n; ++r) { double a = fabs(aug[r][kk]); if (a > best) { best = a; p = r; } }
      pivs = p;
    }
    __syncthreads();
    const int p = pivs;
    if (p != kk) {
      for (int c = tid; c < w; c += 64) { double t = aug[kk][c]; aug[kk][c] = aug[p][c]; aug[p][c] = t; }
    }
    __syncthreads();
    const double ipiv = 1.0 / aug[kk][kk];
    for (int c = tid; c < w; c += 64) aug[kk][c] *= ipiv;
    __syncthreads();
    for (int r = tid; r < n; r += 64) {
      if (r != kk) {
        const double f = aug[r][kk];
        for (int c = kk; c < w; ++c) aug[r][c] -= f * aug[kk][c];
      }
    }
    __syncthreads();
  }

  if (mid == 0) {
    for (int e = tid; e < 16*8; e += 64) ws[WS_NX0 + e] = (float)aug[e >> 3][n + 16 + (e & 7)];
  } else if (mid == 1) {
    for (int e = tid; e < 16*9; e += 64) ws[WS_NY0 + e] = (float)aug[e / 9][n + 16 + (e % 9)];
  } else if (mid == 2) {
    for (int e = tid; e < 256;  e += 64) ws[WS_MX + e] = (float)aug[e >> 4][n + (e & 15)];
    for (int e = tid; e < 16*8; e += 64) ws[WS_NX + e] = (float)aug[e >> 3][n + 16 + (e & 7)];
  } else {
    for (int e = tid; e < 256;  e += 64) ws[WS_MY + e] = (float)aug[e >> 4][n + (e & 15)];
    for (int e = tid; e < 16*9; e += 64) ws[WS_NY + e] = (float)aug[e / 9][n + 16 + (e % 9)];
  }

  if (mid >= 2) {
    for (int e = tid; e < 256; e += 64) {
      const int j = e >> 4, kk = e & 15;
      double s = 0.0;
      for (int mm = 0; mm < 16; ++mm) s += aug[j][n + mm] * G[mm][kk];
      ws[(mid == 2 ? WS_MGX : WS_MGY) + e] = (float)s;
    }
  }
}

// ---- main kernel: ONE wave (64 threads) per problem, 2 timesteps/thread ----
__global__ __launch_bounds__(64, 4) void planner_main(
    const float* __restrict__ P, const float* __restrict__ Pd, const float* __restrict__ Pdd,
    const float* __restrict__ init_state, const float* __restrict__ fin_state,
    const float* __restrict__ cobs, const float* __restrict__ vobs,
    const float* __restrict__ yub_g, const float* __restrict__ ylb_g,
    const float* __restrict__ lamx_g, const float* __restrict__ lamy_g,
    const float* __restrict__ cxp_g, const float* __restrict__ cyp_g,
    const float* __restrict__ ws, float* __restrict__ out)
{
  const int b    = blockIdx.x;
  const int tid  = threadIdx.x;        // timesteps t0 = tid, t1 = tid + 64
  const int o32  = tid & 31;           // reduction row owned (dup over cc)
  const int cc   = tid >> 5;
  const int rr   = tid & 15;           // solve row
  const int side = (tid >> 4) & 1;     // 0 = x-side, 1 = y-side
  const int q4   = tid >> 2;           // quad index (0..15)
  const int k    = tid & 3;            // lane-in-quad

  __shared__ alignas(16) float red[16*RS];  // [quad][o], 2.3 KB
  __shared__ alignas(16) float cL[32];
  __shared__ alignas(16) float hL[32];

  // basis rows for both timesteps (j-pair packed)
  f32x2 Pr2[2][8], Pdr2[2][8], Pddr2[2][8];
  #pragma unroll
  for (int u = 0; u < 2; ++u) {
    const int t = tid + 64*u;
    #pragma unroll
    for (int q = 0; q < 4; ++q) {
      F4 a, bb, ce;
      a.v  = *reinterpret_cast<const float4*>(P   + t*16 + 4*q);
      bb.v = *reinterpret_cast<const float4*>(Pd  + t*16 + 4*q);
      ce.v = *reinterpret_cast<const float4*>(Pdd + t*16 + 4*q);
      Pr2  [u][2*q+0] = f32x2{a.f[0],  a.f[1]};  Pr2  [u][2*q+1] = f32x2{a.f[2],  a.f[3]};
      Pdr2 [u][2*q+0] = f32x2{bb.f[0], bb.f[1]}; Pdr2 [u][2*q+1] = f32x2{bb.f[2], bb.f[3]};
      Pddr2[u][2*q+0] = f32x2{ce.f[0], ce.f[1]}; Pddr2[u][2*q+1] = f32x2{ce.f[2], ce.f[3]};
    }
  }

  // pre-scaled obstacle trajectories at both timesteps (obstacle-pair packed)
  f32x2 xot0[5], yot0[5], xot1[5], yot1[5];
  {
    const float tt0 = (float)tid        * (10.0f/127.0f);
    const float tt1 = (float)(tid + 64) * (10.0f/127.0f);
    #pragma unroll
    for (int o5 = 0; o5 < 5; ++o5) {
      const int o = 2*o5;
      const float xo0 = cobs[b*20+o],    xo1 = cobs[b*20+o+1];
      const float yo0 = cobs[b*20+10+o], yo1 = cobs[b*20+11+o];
      const float vx0 = vobs[b*20+o],    vx1 = vobs[b*20+o+1];
      const float vy0 = vobs[b*20+10+o], vy1 = vobs[b*20+11+o];
      xot0[o5] = f32x2{3.2f*fmaf(vx0,tt0,xo0), 3.2f*fmaf(vx1,tt0,xo1)};
      yot0[o5] = f32x2{6.0f*fmaf(vy0,tt0,yo0), 6.0f*fmaf(vy1,tt0,yo1)};
      xot1[o5] = f32x2{3.2f*fmaf(vx0,tt1,xo0), 3.2f*fmaf(vx1,tt1,xo1)};
      yot1[o5] = f32x2{6.0f*fmaf(vy0,tt1,yo0), 6.0f*fmaf(vy1,tt1,yo1)};
    }
  }
  const float yub = yub_g[b], ylb = ylb_g[b];

  // lambda carry for owned reduction row (dup across cc)
  float lam = (o32 < 16) ? lamx_g[b*16 + o32] : lamy_g[b*16 + (o32 - 16)];

  // per-lane solve-row setup: const term, initial c (row rr, side)
  float constv, myc;
  {
    float beq[9];
    const float vi  = init_state[b*4+2];
    const float psi = init_state[b*4+3];
    if (side == 0) {
      beq[0] = init_state[b*4+0];
      beq[1] = vi * cosf(psi);
      beq[2] = 0.f;
      beq[3] = fin_state[b*3+0];
      #pragma unroll
      for (int i2 = 0; i2 < 4; ++i2) beq[4+i2] = cxp_g[b*4+i2];
      beq[8] = 0.f;                      // pad: multiplies in-bounds junk * 0
    } else {
      beq[0] = init_state[b*4+1];
      beq[1] = vi * sinf(psi);
      beq[2] = 0.f;
      beq[3] = fin_state[b*3+1];
      beq[4] = 0.f;
      #pragma unroll
      for (int i2 = 0; i2 < 4; ++i2) beq[5+i2] = cyp_g[b*4+i2];
    }
    const int nstr = side ? 9 : 8;
    const float* Np  = ws + (side ? WS_NY  : WS_NX ) + rr*nstr;
    const float* N0p = ws + (side ? WS_NY0 : WS_NX0) + rr*nstr;
    float cv = 0.f, c0 = 0.f;
    #pragma unroll
    for (int mm = 0; mm < 9; ++mm) {
      const float bm = beq[mm];
      cv = fmaf(Np[mm],  bm, cv);
      c0 = fmaf(N0p[mm], bm, c0);
    }
    constv = cv;
    myc    = c0;
  }
  if (tid < 32) cL[tid] = myc;           // same-wave DS ordering

  const float* Mrow  = ws + (side ? WS_MY  : WS_MX ) + rr*16;
  const float* MGrow = ws + (side ? WS_MGY : WS_MGX) + rr*16;
  const bool  kb2 = (k & 2) != 0;
  const int   k1  = k & 1;

  #pragma unroll 1
  for (int it = 0; it < MAXIT; ++it) {
    __builtin_amdgcn_wave_barrier();
    // ---- forward matvecs, t0 then t1 (6 packed accumulators reused) ----
    float x0,y0,xd0,yd0,xdd0,ydd0, x1,y1,xd1,yd1,xdd1,ydd1;
    #pragma unroll
    for (int u = 0; u < 2; ++u) {
      f32x2 xv{},yv{},xdv{},ydv{},xddv{},yddv{};
      #pragma unroll
      for (int q = 0; q < 4; ++q) {
        F4 cx4, cy4;
        cx4.v = *reinterpret_cast<const float4*>(&cL[4*q]);
        cy4.v = *reinterpret_cast<const float4*>(&cL[16 + 4*q]);
        const f32x2 c01 = f32x2{cx4.f[0], cx4.f[1]}, c23 = f32x2{cx4.f[2], cx4.f[3]};
        const f32x2 d01 = f32x2{cy4.f[0], cy4.f[1]}, d23 = f32x2{cy4.f[2], cy4.f[3]};
        xv   = pfma(Pr2  [u][2*q], c01, xv);   xv   = pfma(Pr2  [u][2*q+1], c23, xv);
        yv   = pfma(Pr2  [u][2*q], d01, yv);   yv   = pfma(Pr2  [u][2*q+1], d23, yv);
        xdv  = pfma(Pdr2 [u][2*q], c01, xdv);  xdv  = pfma(Pdr2 [u][2*q+1], c23, xdv);
        ydv  = pfma(Pdr2 [u][2*q], d01, ydv);  ydv  = pfma(Pdr2 [u][2*q+1], d23, ydv);
        xddv = pfma(Pddr2[u][2*q], c01, xddv); xddv = pfma(Pddr2[u][2*q+1], c23, xddv);
        yddv = pfma(Pddr2[u][2*q], d01, yddv); yddv = pfma(Pddr2[u][2*q+1], d23, yddv);
      }
      if (u == 0) {
        x0=xv.x+xv.y; y0=yv.x+yv.y; xd0=xdv.x+xdv.y; yd0=ydv.x+ydv.y;
        xdd0=xddv.x+xddv.y; ydd0=yddv.x+yddv.y;
      } else {
        x1=xv.x+xv.y; y1=yv.x+yv.y; xd1=xdv.x+xdv.y; yd1=ydv.x+ydv.y;
        xdd1=xddv.x+xddv.y; ydd1=yddv.x+yddv.y;
      }
    }

    // ---- projections ----
    const float ria0 = rsqrtf(fmaxf(fmaf(xdd0,xdd0,ydd0*ydd0), 1e-36f));
    const float ga10 = 1.0f - fminf(1.0f, 18.0f*ria0);
    const float riv0 = rsqrtf(fmaxf(fmaf(xd0,xd0,yd0*yd0), 1e-36f));
    const float gv10 = 1.0f - fminf(fmaxf(1.0f, 0.1f*riv0), 30.0f*riv0);
    const float ria1 = rsqrtf(fmaxf(fmaf(xdd1,xdd1,ydd1*ydd1), 1e-36f));
    const float ga11 = 1.0f - fminf(1.0f, 18.0f*ria1);
    const float riv1 = rsqrtf(fmaxf(fmaf(xd1,xd1,yd1*yd1), 1e-36f));
    const float gv11 = 1.0f - fminf(fmaxf(1.0f, 0.1f*riv1), 30.0f*riv1);

    // ---- obstacles ----
    f32x2 Sx0{}, Sy0{}, Sx1{}, Sy1{};
    {
      const f32x2 xb0 = f32x2{3.2f*x0, 3.2f*x0}, yb0 = f32x2{6.0f*y0, 6.0f*y0};
      const f32x2 xb1 = f32x2{3.2f*x1, 3.2f*x1}, yb1 = f32x2{6.0f*y1, 6.0f*y1};
      #pragma unroll
      for (int o5 = 0; o5 < 5; ++o5) {
        const f32x2 bw0 = xb0 - xot0[o5], aw0 = yb0 - yot0[o5];
        const f32x2 bw1 = xb1 - xot1[o5], aw1 = yb1 - yot1[o5];
        const f32x2 r20 = pfma(bw0,bw0,aw0*aw0);
        const f32x2 r21 = pfma(bw1,bw1,aw1*aw1);
        const f32x2 ee0 = f32x2{
          fmaxf(fmaf(19.2f, rsqrtf(fmaxf(r20.x,1e-36f)), -1.0f), 0.f),
          fmaxf(fmaf(19.2f, rsqrtf(fmaxf(r20.y,1e-36f)), -1.0f), 0.f)};
        const f32x2 ee1 = f32x2{
          fmaxf(fmaf(19.2f, rsqrtf(fmaxf(r21.x,1e-36f)), -1.0f), 0.f),
          fmaxf(fmaf(19.2f, rsqrtf(fmaxf(r21.y,1e-36f)), -1.0f), 0.f)};
        Sx0 = pfma(ee0, bw0, Sx0);  Sy0 = pfma(ee0, aw0, Sy0);
        Sx1 = pfma(ee1, bw1, Sx1);  Sy1 = pfma(ee1, aw1, Sy1);
      }
    }
    const float c0p0 = -(Sx0.x+Sx0.y)*0.3125f;
    const float rln0 = fmaxf(y0-yub,0.f) - fmaxf(ylb-y0,0.f);
    const float c2p0 = rln0 - (Sy0.x+Sy0.y)*(1.0f/6.0f);
    const float c0dd0 = xdd0*ga10, c0d0 = xd0*gv10;
    const float c2dd0 = ydd0*ga10, c2d0 = yd0*gv10;
    const float c0p1 = -(Sx1.x+Sx1.y)*0.3125f;
    const float rln1 = fmaxf(y1-yub,0.f) - fmaxf(ylb-y1,0.f);
    const float c2p1 = rln1 - (Sy1.x+Sy1.y)*(1.0f/6.0f);
    const float c0dd1 = xdd1*ga11, c0d1 = xd1*gv11;
    const float c2dd1 = ydd1*ga11, c2d1 = yd1*gv11;

    // ---- back-projection (pre-summed over own 2 t's) + quad DPP reduce ----
    float outv[8];
    #pragma unroll
    for (int s2 = 0; s2 < 8; ++s2) outv[s2] = 0.f;
    {
      const f32x2 A00{c0dd0,c0dd0}, D00{c0d0,c0d0}, Q00{c0p0,c0p0};
      const f32x2 A20{c2dd0,c2dd0}, D20{c2d0,c2d0}, Q20{c2p0,c2p0};
      const f32x2 A01{c0dd1,c0dd1}, D01{c0d1,c0d1}, Q01{c0p1,c0p1};
      const f32x2 A21{c2dd1,c2dd1}, D21{c2d1,c2d1}, Q21{c2p1,c2p1};
      #pragma unroll
      for (int j2 = 0; j2 < 8; ++j2) {
        f32x2 vx = pfma(A00, Pddr2[0][j2], pfma(D00, Pdr2[0][j2], Q00*Pr2[0][j2]));
        vx = pfma(A01, Pddr2[1][j2], pfma(D01, Pdr2[1][j2], pfma(Q01, Pr2[1][j2], vx)));
        f32x2 vy = pfma(A20, Pddr2[0][j2], pfma(D20, Pdr2[0][j2], Q20*Pr2[0][j2]));
        vy = pfma(A21, Pddr2[1][j2], pfma(D21, Pdr2[1][j2], pfma(Q21, Pr2[1][j2], vy)));
        // quad sums (each covers 8 timesteps)
        const float qx0 = qsum(vx.x), qx1 = qsum(vx.y);
        const float qy0 = qsum(vy.x), qy1 = qsum(vy.y);
        // lane k of each quad keeps o-chunk [8k, 8k+8)
        const float s0 = kb2 ? qy0 : qx0;
        const float s1 = kb2 ? qy1 : qx1;
        const bool match = (k1 == (j2 >> 2));
        const int  sb = 2*(j2 & 3);
        outv[sb]   = match ? s0 : outv[sb];
        outv[sb+1] = match ? s1 : outv[sb+1];
      }
    }
    __builtin_amdgcn_wave_barrier();
    {
      float* wr = red + q4*RS + 8*k;
      *reinterpret_cast<float4*>(wr)     = float4{outv[0],outv[1],outv[2],outv[3]};
      *reinterpret_cast<float4*>(wr + 4) = float4{outv[4],outv[5],outv[6],outv[7]};
    }
    __builtin_amdgcn_wave_barrier();

    // ---- reduce 16 quad-rows for owned column o32 ----
    float h;
    {
      const float* rd = red + (cc*8)*RS + o32;
      float s = 0.f;
      #pragma unroll
      for (int i = 0; i < 8; ++i) s += rd[i*RS];
      s += __shfl_xor(s, 32);
      lam -= s;
      h = lam - s;                         // lam_old - 2S
    }
    __builtin_amdgcn_wave_barrier();
    if (tid < 32) hL[tid] = h;
    __builtin_amdgcn_wave_barrier();

    // ---- fused solve: c' = MG*c + M*h + const ----
    {
      f32x2 accv{};
      #pragma unroll
      for (int q = 0; q < 4; ++q) {
        F4 m4, g4, h4, c4;
        m4.v = *reinterpret_cast<const float4*>(Mrow  + 4*q);
        g4.v = *reinterpret_cast<const float4*>(MGrow + 4*q);
        h4.v = *reinterpret_cast<const float4*>(&hL[side*16 + 4*q]);
        c4.v = *reinterpret_cast<const float4*>(&cL[side*16 + 4*q]);
        accv = pfma(f32x2{m4.f[0],m4.f[1]}, f32x2{h4.f[0],h4.f[1]}, accv);
        accv = pfma(f32x2{g4.f[0],g4.f[1]}, f32x2{c4.f[0],c4.f[1]}, accv);
        accv = pfma(f32x2{m4.f[2],m4.f[3]}, f32x2{h4.f[2],h4.f[3]}, accv);
        accv = pfma(f32x2{g4.f[2],g4.f[3]}, f32x2{c4.f[2],c4.f[3]}, accv);
      }
      myc = constv + accv.x + accv.y;
    }
    __builtin_amdgcn_wave_barrier();
    if (tid < 32) cL[tid] = myc;           // next iter reads (same-wave order)
  }

  if (tid < 32) out[b*32 + tid] = myc;
}

extern "C" void kernel_launch(void* const* d_in, const int* in_sizes, int n_in,
                              void* d_out, int out_size, void* d_ws, size_t ws_size,
                              hipStream_t stream) {
  const float* P    = (const float*)d_in[0];
  const float* Pd   = (const float*)d_in[1];
  const float* Pdd  = (const float*)d_in[2];
  const float* init = (const float*)d_in[3];
  const float* fin  = (const float*)d_in[4];
  const float* cobs = (const float*)d_in[5];
  const float* vobs = (const float*)d_in[6];
  const float* yub  = (const float*)d_in[7];
  const float* ylb  = (const float*)d_in[8];
  const float* lamx = (const float*)d_in[9];
  const float* lamy = (const float*)d_in[10];
  const float* cxp  = (const float*)d_in[11];
  const float* cyp  = (const float*)d_in[12];
  float* ws  = (float*)d_ws;
  float* o   = (float*)d_out;

  planner_setup<<<dim3(4), dim3(64), 0, stream>>>(P, Pd, Pdd, ws);
  planner_main<<<dim3(NBATCH), dim3(64), 0, stream>>>(
      P, Pd, Pdd, init, fin, cobs, vobs, yub, ylb, lamx, lamy, cxp, cyp, ws, o);
}

// Round 11
// 904.776 us; speedup vs baseline: 1.0058x; 1.0058x over previous
//
#include <hip/hip_runtime.h>
#include <math.h>

#define NBATCH 4096
#define TNUM   128
#define NOBSC  10
#define MAXIT  30

// ws layout (floats)
#define WS_MX   0      // 16x16
#define WS_MY   256    // 16x16
#define WS_MGX  512    // 16x16  (Mx*Gx)
#define WS_MGY  768    // 16x16  (My*Gy)
#define WS_NX   1024   // 16x8
#define WS_NY   1152   // 16x9
#define WS_NX0  1296   // 16x8
#define WS_NY0  1424   // 16x9
// total 1568 floats

#define RS 36          // red row stride (16 quad-rows x 32 cols + pad)

typedef float f32x2 __attribute__((ext_vector_type(2)));
union F4 { float4 v; float f[4]; };

__device__ __forceinline__ f32x2 pfma(f32x2 a, f32x2 b, f32x2 c) {
  return __builtin_elementwise_fma(a, b, c);
}

// quad-lane (4 consecutive lanes) all-reduce sum via DPP (VALU pipe, no LDS)
__device__ __forceinline__ float qsum(float v) {
  float s = v + __int_as_float(__builtin_amdgcn_update_dpp(
      0, __float_as_int(v), 0xB1, 0xF, 0xF, true));   // quad_perm [1,0,3,2] = xor1
  s = s + __int_as_float(__builtin_amdgcn_update_dpp(
      0, __float_as_int(s), 0x4E, 0xF, 0xF, true));   // quad_perm [2,3,0,1] = xor2
  return s;
}

// ---------------- setup kernel: build + invert KKT matrices (fp64 GJ) -------
__global__ __launch_bounds__(64) void planner_setup(
    const float* __restrict__ P, const float* __restrict__ Pd, const float* __restrict__ Pdd,
    float* __restrict__ ws)
{
  const int mid = blockIdx.x;   // 0: (cost_sm,Ax)->Nx0  1: (cost_sm,Ay)->Ny0
                                // 2: (cost_x,Ax)->Mx,Nx,MGx 3: (cost_y,Ay)->My,Ny,MGy
  const int tid = threadIdx.x;
  __shared__ double C[16][16];
  __shared__ double G[16][16];
  __shared__ double Ae[9][16];
  __shared__ double aug[25][50];
  __shared__ double fcol[32];
  __shared__ int pivs;

  const bool isY = (mid & 1);
  const int  m   = isY ? 9 : 8;
  const int  n   = 16 + m;
  const int  w   = 2 * n;

  for (int e = tid; e < 256; e += 64) {
    const int j = e >> 4, kk = e & 15;
    double gdd = 0.0, gd = 0.0, g0 = 0.0;
    for (int t = 0; t < TNUM; ++t) {
      gdd += (double)Pdd[t*16+j] * (double)Pdd[t*16+kk];
      gd  += (double)Pd [t*16+j] * (double)Pd [t*16+kk];
      g0  += (double)P  [t*16+j] * (double)P  [t*16+kk];
    }
    const double cs = 100.0 * (gdd + ((j == kk) ? 0.1 : 0.0));
    const double g  = gdd + gd + (isY ? 12.0 : 10.0) * g0;
    G[j][kk] = g;
    C[j][kk] = (mid >= 2) ? (cs + g) : cs;
  }
  if (tid < 16) {
    const int j = tid;
    Ae[0][j] = (double)P  [0*16+j];
    Ae[1][j] = (double)Pd [0*16+j];
    Ae[2][j] = (double)Pdd[0*16+j];
    if (!isY) {
      Ae[3][j] = (double)Pd[127*16+j];
      for (int r = 4; r < 8; ++r) Ae[r][j] = (j == r) ? 1.0 : 0.0;
    } else {
      Ae[3][j] = (double)P [127*16+j];
      Ae[4][j] = (double)Pd[127*16+j];
      for (int r = 5; r < 9; ++r) Ae[r][j] = (j == (r-1)) ? 1.0 : 0.0;
    }
  }
  __syncthreads();

  for (int e = tid; e < n * w; e += 64) {
    const int r = e / w, c = e % w;
    double val;
    if (c < n) {
      if (r < 16) val = (c < 16) ? C[r][c] : Ae[c-16][r];
      else        val = (c < 16) ? Ae[r-16][c] : 0.0;
    } else {
      val = ((c - n) == r) ? 1.0 : 0.0;
    }
    aug[r][c] = val;
  }
  __syncthreads();

  // Gauss-Jordan with partial pivoting (wave-parallel)
  const int hw  = (w + 1) >> 1;       // half-row width
  const int rw  = tid >> 1;           // row handled by this lane (2 lanes/row)
  const int hf  = tid & 1;
  for (int kk = 0; kk < n; ++kk) {
    // parallel argmax pivot over rows kk..n-1 (smallest index on ties)
    {
      double a = (tid >= kk && tid < n) ? fabs(aug[tid][kk]) : -1.0;
      int p = tid;
      #pragma unroll
      for (int off = 1; off < 64; off <<= 1) {
        const double oa = __shfl_xor(a, off);
        const int    op = __shfl_xor(p, off);
        if (oa > a || (oa == a && op < p)) { a = oa; p = op; }
      }
      if (tid == 0) pivs = p;
    }
    __syncthreads();
    const int p = pivs;
    if (p != kk) {
      for (int c = tid; c < w; c += 64) { double t = aug[kk][c]; aug[kk][c] = aug[p][c]; aug[p][c] = t; }
    }
    __syncthreads();
    const double ipiv = 1.0 / aug[kk][kk];
    for (int c = tid; c < w; c += 64) aug[kk][c] *= ipiv;
    if (tid < n) fcol[tid] = aug[tid][kk];   // fcol[kk] races with scale but is unused
    __syncthreads();
    if (rw < n && rw != kk) {
      const double f = fcol[rw];
      const int c0 = hf * hw;
      const int c1 = (c0 + hw < w) ? (c0 + hw) : w;
      for (int c = c0; c < c1; ++c) aug[rw][c] -= f * aug[kk][c];
    }
    __syncthreads();
  }

  if (mid == 0) {
    for (int e = tid; e < 16*8; e += 64) ws[WS_NX0 + e] = (float)aug[e >> 3][n + 16 + (e & 7)];
  } else if (mid == 1) {
    for (int e = tid; e < 16*9; e += 64) ws[WS_NY0 + e] = (float)aug[e / 9][n + 16 + (e % 9)];
  } else if (mid == 2) {
    for (int e = tid; e < 256;  e += 64) ws[WS_MX + e] = (float)aug[e >> 4][n + (e & 15)];
    for (int e = tid; e < 16*8; e += 64) ws[WS_NX + e] = (float)aug[e >> 3][n + 16 + (e & 7)];
  } else {
    for (int e = tid; e < 256;  e += 64) ws[WS_MY + e] = (float)aug[e >> 4][n + (e & 15)];
    for (int e = tid; e < 16*9; e += 64) ws[WS_NY + e] = (float)aug[e / 9][n + 16 + (e % 9)];
  }

  if (mid >= 2) {
    for (int e = tid; e < 256; e += 64) {
      const int j = e >> 4, kk = e & 15;
      double s = 0.0;
      for (int mm = 0; mm < 16; ++mm) s += aug[j][n + mm] * G[mm][kk];
      ws[(mid == 2 ? WS_MGX : WS_MGY) + e] = (float)s;
    }
  }
}

// ---- main kernel: ONE wave (64 threads) per problem, 2 timesteps/thread ----
__global__ __launch_bounds__(64) __attribute__((amdgpu_waves_per_eu(4, 4)))
void planner_main(
    const float* __restrict__ P, const float* __restrict__ Pd, const float* __restrict__ Pdd,
    const float* __restrict__ init_state, const float* __restrict__ fin_state,
    const float* __restrict__ cobs, const float* __restrict__ vobs,
    const float* __restrict__ yub_g, const float* __restrict__ ylb_g,
    const float* __restrict__ lamx_g, const float* __restrict__ lamy_g,
    const float* __restrict__ cxp_g, const float* __restrict__ cyp_g,
    const float* __restrict__ ws, float* __restrict__ out)
{
  const int b    = blockIdx.x;
  const int tid  = threadIdx.x;        // timesteps t0 = tid, t1 = tid + 64
  const int o32  = tid & 31;           // reduction row owned (dup over cc)
  const int cc   = tid >> 5;
  const int rr   = tid & 15;           // solve row
  const int side = (tid >> 4) & 1;     // 0 = x-side, 1 = y-side
  const int q4   = tid >> 2;           // quad index (0..15)
  const int k    = tid & 3;            // lane-in-quad

  __shared__ alignas(16) float red[16*RS];  // [quad][o], 2.3 KB
  __shared__ alignas(16) float cL[32];
  __shared__ alignas(16) float hL[32];

  // basis rows for both timesteps (j-pair packed)
  f32x2 Pr2[2][8], Pdr2[2][8], Pddr2[2][8];
  #pragma unroll
  for (int u = 0; u < 2; ++u) {
    const int t = tid + 64*u;
    #pragma unroll
    for (int q = 0; q < 4; ++q) {
      F4 a, bb, ce;
      a.v  = *reinterpret_cast<const float4*>(P   + t*16 + 4*q);
      bb.v = *reinterpret_cast<const float4*>(Pd  + t*16 + 4*q);
      ce.v = *reinterpret_cast<const float4*>(Pdd + t*16 + 4*q);
      Pr2  [u][2*q+0] = f32x2{a.f[0],  a.f[1]};  Pr2  [u][2*q+1] = f32x2{a.f[2],  a.f[3]};
      Pdr2 [u][2*q+0] = f32x2{bb.f[0], bb.f[1]}; Pdr2 [u][2*q+1] = f32x2{bb.f[2], bb.f[3]};
      Pddr2[u][2*q+0] = f32x2{ce.f[0], ce.f[1]}; Pddr2[u][2*q+1] = f32x2{ce.f[2], ce.f[3]};
    }
  }

  // pre-scaled obstacle trajectories at both timesteps (obstacle-pair packed)
  f32x2 xot0[5], yot0[5], xot1[5], yot1[5];
  {
    const float tt0 = (float)tid        * (10.0f/127.0f);
    const float tt1 = (float)(tid + 64) * (10.0f/127.0f);
    #pragma unroll
    for (int o5 = 0; o5 < 5; ++o5) {
      const int o = 2*o5;
      const float xo0 = cobs[b*20+o],    xo1 = cobs[b*20+o+1];
      const float yo0 = cobs[b*20+10+o], yo1 = cobs[b*20+11+o];
      const float vx0 = vobs[b*20+o],    vx1 = vobs[b*20+o+1];
      const float vy0 = vobs[b*20+10+o], vy1 = vobs[b*20+11+o];
      xot0[o5] = f32x2{3.2f*fmaf(vx0,tt0,xo0), 3.2f*fmaf(vx1,tt0,xo1)};
      yot0[o5] = f32x2{6.0f*fmaf(vy0,tt0,yo0), 6.0f*fmaf(vy1,tt0,yo1)};
      xot1[o5] = f32x2{3.2f*fmaf(vx0,tt1,xo0), 3.2f*fmaf(vx1,tt1,xo1)};
      yot1[o5] = f32x2{6.0f*fmaf(vy0,tt1,yo0), 6.0f*fmaf(vy1,tt1,yo1)};
    }
  }
  const float yub = yub_g[b], ylb = ylb_g[b];

  // lambda carry for owned reduction row (dup across cc)
  float lam = (o32 < 16) ? lamx_g[b*16 + o32] : lamy_g[b*16 + (o32 - 16)];

  // per-lane solve-row setup: const term, initial c (row rr, side)
  float constv, myc;
  {
    float beq[9];
    const float vi  = init_state[b*4+2];
    const float psi = init_state[b*4+3];
    if (side == 0) {
      beq[0] = init_state[b*4+0];
      beq[1] = vi * cosf(psi);
      beq[2] = 0.f;
      beq[3] = fin_state[b*3+0];
      #pragma unroll
      for (int i2 = 0; i2 < 4; ++i2) beq[4+i2] = cxp_g[b*4+i2];
      beq[8] = 0.f;                      // pad: multiplies in-bounds junk * 0
    } else {
      beq[0] = init_state[b*4+1];
      beq[1] = vi * sinf(psi);
      beq[2] = 0.f;
      beq[3] = fin_state[b*3+1];
      beq[4] = 0.f;
      #pragma unroll
      for (int i2 = 0; i2 < 4; ++i2) beq[5+i2] = cyp_g[b*4+i2];
    }
    const int nstr = side ? 9 : 8;
    const float* Np  = ws + (side ? WS_NY  : WS_NX ) + rr*nstr;
    const float* N0p = ws + (side ? WS_NY0 : WS_NX0) + rr*nstr;
    float cv = 0.f, c0 = 0.f;
    #pragma unroll
    for (int mm = 0; mm < 9; ++mm) {
      const float bm = beq[mm];
      cv = fmaf(Np[mm],  bm, cv);
      c0 = fmaf(N0p[mm], bm, c0);
    }
    constv = cv;
    myc    = c0;
  }
  if (tid < 32) cL[tid] = myc;           // same-wave DS ordering

  const float* Mrow  = ws + (side ? WS_MY  : WS_MX ) + rr*16;
  const float* MGrow = ws + (side ? WS_MGY : WS_MGX) + rr*16;
  const bool  kb2 = (k & 2) != 0;
  const int   k1  = k & 1;

  #pragma unroll 1
  for (int it = 0; it < MAXIT; ++it) {
    __builtin_amdgcn_wave_barrier();
    // ---- forward matvecs, t0 then t1 (6 packed accumulators reused) ----
    float x0,y0,xd0,yd0,xdd0,ydd0, x1,y1,xd1,yd1,xdd1,ydd1;
    #pragma unroll
    for (int u = 0; u < 2; ++u) {
      f32x2 xv{},yv{},xdv{},ydv{},xddv{},yddv{};
      #pragma unroll
      for (int q = 0; q < 4; ++q) {
        F4 cx4, cy4;
        cx4.v = *reinterpret_cast<const float4*>(&cL[4*q]);
        cy4.v = *reinterpret_cast<const float4*>(&cL[16 + 4*q]);
        const f32x2 c01 = f32x2{cx4.f[0], cx4.f[1]}, c23 = f32x2{cx4.f[2], cx4.f[3]};
        const f32x2 d01 = f32x2{cy4.f[0], cy4.f[1]}, d23 = f32x2{cy4.f[2], cy4.f[3]};
        xv   = pfma(Pr2  [u][2*q], c01, xv);   xv   = pfma(Pr2  [u][2*q+1], c23, xv);
        yv   = pfma(Pr2  [u][2*q], d01, yv);   yv   = pfma(Pr2  [u][2*q+1], d23, yv);
        xdv  = pfma(Pdr2 [u][2*q], c01, xdv);  xdv  = pfma(Pdr2 [u][2*q+1], c23, xdv);
        ydv  = pfma(Pdr2 [u][2*q], d01, ydv);  ydv  = pfma(Pdr2 [u][2*q+1], d23, ydv);
        xddv = pfma(Pddr2[u][2*q], c01, xddv); xddv = pfma(Pddr2[u][2*q+1], c23, xddv);
        yddv = pfma(Pddr2[u][2*q], d01, yddv); yddv = pfma(Pddr2[u][2*q+1], d23, yddv);
      }
      if (u == 0) {
        x0=xv.x+xv.y; y0=yv.x+yv.y; xd0=xdv.x+xdv.y; yd0=ydv.x+ydv.y;
        xdd0=xddv.x+xddv.y; ydd0=yddv.x+yddv.y;
      } else {
        x1=xv.x+xv.y; y1=yv.x+yv.y; xd1=xdv.x+xdv.y; yd1=ydv.x+ydv.y;
        xdd1=xddv.x+xddv.y; ydd1=yddv.x+yddv.y;
      }
    }

    // ---- projections ----
    const float ria0 = rsqrtf(fmaxf(fmaf(xdd0,xdd0,ydd0*ydd0), 1e-36f));
    const float ga10 = 1.0f - fminf(1.0f, 18.0f*ria0);
    const float riv0 = rsqrtf(fmaxf(fmaf(xd0,xd0,yd0*yd0), 1e-36f));
    const float gv10 = 1.0f - fminf(fmaxf(1.0f, 0.1f*riv0), 30.0f*riv0);
    const float ria1 = rsqrtf(fmaxf(fmaf(xdd1,xdd1,ydd1*ydd1), 1e-36f));
    const float ga11 = 1.0f - fminf(1.0f, 18.0f*ria1);
    const float riv1 = rsqrtf(fmaxf(fmaf(xd1,xd1,yd1*yd1), 1e-36f));
    const float gv11 = 1.0f - fminf(fmaxf(1.0f, 0.1f*riv1), 30.0f*riv1);

    // ---- obstacles ----
    f32x2 Sx0{}, Sy0{}, Sx1{}, Sy1{};
    {
      const f32x2 xb0 = f32x2{3.2f*x0, 3.2f*x0}, yb0 = f32x2{6.0f*y0, 6.0f*y0};
      const f32x2 xb1 = f32x2{3.2f*x1, 3.2f*x1}, yb1 = f32x2{6.0f*y1, 6.0f*y1};
      #pragma unroll
      for (int o5 = 0; o5 < 5; ++o5) {
        const f32x2 bw0 = xb0 - xot0[o5], aw0 = yb0 - yot0[o5];
        const f32x2 bw1 = xb1 - xot1[o5], aw1 = yb1 - yot1[o5];
        const f32x2 r20 = pfma(bw0,bw0,aw0*aw0);
        const f32x2 r21 = pfma(bw1,bw1,aw1*aw1);
        const f32x2 ee0 = f32x2{
          fmaxf(fmaf(19.2f, rsqrtf(fmaxf(r20.x,1e-36f)), -1.0f), 0.f),
          fmaxf(fmaf(19.2f, rsqrtf(fmaxf(r20.y,1e-36f)), -1.0f), 0.f)};
        const f32x2 ee1 = f32x2{
          fmaxf(fmaf(19.2f, rsqrtf(fmaxf(r21.x,1e-36f)), -1.0f), 0.f),
          fmaxf(fmaf(19.2f, rsqrtf(fmaxf(r21.y,1e-36f)), -1.0f), 0.f)};
        Sx0 = pfma(ee0, bw0, Sx0);  Sy0 = pfma(ee0, aw0, Sy0);
        Sx1 = pfma(ee1, bw1, Sx1);  Sy1 = pfma(ee1, aw1, Sy1);
      }
    }
    const float c0p0 = -(Sx0.x+Sx0.y)*0.3125f;
    const float rln0 = fmaxf(y0-yub,0.f) - fmaxf(ylb-y0,0.f);
    const float c2p0 = rln0 - (Sy0.x+Sy0.y)*(1.0f/6.0f);
    const float c0dd0 = xdd0*ga10, c0d0 = xd0*gv10;
    const float c2dd0 = ydd0*ga10, c2d0 = yd0*gv10;
    const float c0p1 = -(Sx1.x+Sx1.y)*0.3125f;
    const float rln1 = fmaxf(y1-yub,0.f) - fmaxf(ylb-y1,0.f);
    const float c2p1 = rln1 - (Sy1.x+Sy1.y)*(1.0f/6.0f);
    const float c0dd1 = xdd1*ga11, c0d1 = xd1*gv11;
    const float c2dd1 = ydd1*ga11, c2d1 = yd1*gv11;

    // ---- back-projection (pre-summed over own 2 t's) + quad DPP reduce ----
    float outv[8];
    #pragma unroll
    for (int s2 = 0; s2 < 8; ++s2) outv[s2] = 0.f;
    {
      const f32x2 A00{c0dd0,c0dd0}, D00{c0d0,c0d0}, Q00{c0p0,c0p0};
      const f32x2 A20{c2dd0,c2dd0}, D20{c2d0,c2d0}, Q20{c2p0,c2p0};
      const f32x2 A01{c0dd1,c0dd1}, D01{c0d1,c0d1}, Q01{c0p1,c0p1};
      const f32x2 A21{c2dd1,c2dd1}, D21{c2d1,c2d1}, Q21{c2p1,c2p1};
      #pragma unroll
      for (int j2 = 0; j2 < 8; ++j2) {
        f32x2 vx = pfma(A00, Pddr2[0][j2], pfma(D00, Pdr2[0][j2], Q00*Pr2[0][j2]));
        vx = pfma(A01, Pddr2[1][j2], pfma(D01, Pdr2[1][j2], pfma(Q01, Pr2[1][j2], vx)));
        f32x2 vy = pfma(A20, Pddr2[0][j2], pfma(D20, Pdr2[0][j2], Q20*Pr2[0][j2]));
        vy = pfma(A21, Pddr2[1][j2], pfma(D21, Pdr2[1][j2], pfma(Q21, Pr2[1][j2], vy)));
        // quad sums (each covers 8 timesteps)
        const float qx0 = qsum(vx.x), qx1 = qsum(vx.y);
        const float qy0 = qsum(vy.x), qy1 = qsum(vy.y);
        // lane k of each quad keeps o-chunk [8k, 8k+8)
        const float s0 = kb2 ? qy0 : qx0;
        const float s1 = kb2 ? qy1 : qx1;
        const bool match = (k1 == (j2 >> 2));
        const int  sb = 2*(j2 & 3);
        outv[sb]   = match ? s0 : outv[sb];
        outv[sb+1] = match ? s1 : outv[sb+1];
      }
    }
    __builtin_amdgcn_wave_barrier();
    {
      float* wr = red + q4*RS + 8*k;
      *reinterpret_cast<float4*>(wr)     = float4{outv[0],outv[1],outv[2],outv[3]};
      *reinterpret_cast<float4*>(wr + 4) = float4{outv[4],outv[5],outv[6],outv[7]};
    }
    __builtin_amdgcn_wave_barrier();

    // ---- reduce 16 quad-rows for owned column o32 ----
    float h;
    {
      const float* rd = red + (cc*8)*RS + o32;
      float s = 0.f;
      #pragma unroll
      for (int i = 0; i < 8; ++i) s += rd[i*RS];
      s += __shfl_xor(s, 32);
      lam -= s;
      h = lam - s;                         // lam_old - 2S
    }
    __builtin_amdgcn_wave_barrier();
    if (tid < 32) hL[tid] = h;
    __builtin_amdgcn_wave_barrier();

    // ---- fused solve: c' = MG*c + M*h + const ----
    {
      f32x2 accv{};
      #pragma unroll
      for (int q = 0; q < 4; ++q) {
        F4 m4, g4, h4, c4;
        m4.v = *reinterpret_cast<const float4*>(Mrow  + 4*q);
        g4.v = *reinterpret_cast<const float4*>(MGrow + 4*q);
        h4.v = *reinterpret_cast<const float4*>(&hL[side*16 + 4*q]);
        c4.v = *reinterpret_cast<const float4*>(&cL[side*16 + 4*q]);
        accv = pfma(f32x2{m4.f[0],m4.f[1]}, f32x2{h4.f[0],h4.f[1]}, accv);
        accv = pfma(f32x2{g4.f[0],g4.f[1]}, f32x2{c4.f[0],c4.f[1]}, accv);
        accv = pfma(f32x2{m4.f[2],m4.f[3]}, f32x2{h4.f[2],h4.f[3]}, accv);
        accv = pfma(f32x2{g4.f[2],g4.f[3]}, f32x2{c4.f[2],c4.f[3]}, accv);
      }
      myc = constv + accv.x + accv.y;
    }
    __builtin_amdgcn_wave_barrier();
    if (tid < 32) cL[tid] = myc;           // next iter reads (same-wave order)
  }

  if (tid < 32) out[b*32 + tid] = myc;
}

extern "C" void kernel_launch(void* const* d_in, const int* in_sizes, int n_in,
                              void* d_out, int out_size, void* d_ws, size_t ws_size,
                              hipStream_t stream) {
  const float* P    = (const float*)d_in[0];
  const float* Pd   = (const float*)d_in[1];
  const float* Pdd  = (const float*)d_in[2];
  const float* init = (const float*)d_in[3];
  const float* fin  = (const float*)d_in[4];
  const float* cobs = (const float*)d_in[5];
  const float* vobs = (const float*)d_in[6];
  const float* yub  = (const float*)d_in[7];
  const float* ylb  = (const float*)d_in[8];
  const float* lamx = (const float*)d_in[9];
  const float* lamy = (const float*)d_in[10];
  const float* cxp  = (const float*)d_in[11];
  const float* cyp  = (const float*)d_in[12];
  float* ws  = (float*)d_ws;
  float* o   = (float*)d_out;

  planner_setup<<<dim3(4), dim3(64), 0, stream>>>(P, Pd, Pdd, ws);
  planner_main<<<dim3(NBATCH), dim3(64), 0, stream>>>(
      P, Pd, Pdd, init, fin, cobs, vobs, yub, ylb, lamx, lamy, cxp, cyp, ws, o);
}

// Round 12
// 218.737 us; speedup vs baseline: 4.1602x; 4.1364x over previous
//
#include <hip/hip_runtime.h>
#include <math.h>

#define NBATCH 4096
#define TNUM   128
#define NOBSC  10
#define MAXIT  30

// ws layout (floats)
#define WS_MX   0      // 16x16
#define WS_MY   256    // 16x16
#define WS_MGX  512    // 16x16  (Mx*Gx)
#define WS_MGY  768    // 16x16  (My*Gy)
#define WS_NX   1024   // 16x8
#define WS_NY   1152   // 16x9
#define WS_NX0  1296   // 16x8
#define WS_NY0  1424   // 16x9
// total 1568 floats

#define RS 36          // red row stride (16 quad-rows x 32 cols + pad)

typedef float f32x2 __attribute__((ext_vector_type(2)));
union F4 { float4 v; float f[4]; };

__device__ __forceinline__ f32x2 pfma(f32x2 a, f32x2 b, f32x2 c) {
  return __builtin_elementwise_fma(a, b, c);
}

// quad-lane (4 consecutive lanes) all-reduce sum via DPP (VALU pipe, no LDS)
__device__ __forceinline__ float qsum(float v) {
  float s = v + __int_as_float(__builtin_amdgcn_update_dpp(
      0, __float_as_int(v), 0xB1, 0xF, 0xF, true));   // quad_perm [1,0,3,2] = xor1
  s = s + __int_as_float(__builtin_amdgcn_update_dpp(
      0, __float_as_int(s), 0x4E, 0xF, 0xF, true));   // quad_perm [2,3,0,1] = xor2
  return s;
}

// ---------------- setup kernel: build + invert KKT matrices (fp64 GJ) -------
__global__ __launch_bounds__(64) void planner_setup(
    const float* __restrict__ P, const float* __restrict__ Pd, const float* __restrict__ Pdd,
    float* __restrict__ ws)
{
  const int mid = blockIdx.x;   // 0: (cost_sm,Ax)->Nx0  1: (cost_sm,Ay)->Ny0
                                // 2: (cost_x,Ax)->Mx,Nx,MGx 3: (cost_y,Ay)->My,Ny,MGy
  const int tid = threadIdx.x;
  __shared__ double C[16][16];
  __shared__ double G[16][16];
  __shared__ double Ae[9][16];
  __shared__ double aug[25][50];
  __shared__ double fcol[32];
  __shared__ int pivs;

  const bool isY = (mid & 1);
  const int  m   = isY ? 9 : 8;
  const int  n   = 16 + m;
  const int  w   = 2 * n;

  for (int e = tid; e < 256; e += 64) {
    const int j = e >> 4, kk = e & 15;
    double gdd = 0.0, gd = 0.0, g0 = 0.0;
    for (int t = 0; t < TNUM; ++t) {
      gdd += (double)Pdd[t*16+j] * (double)Pdd[t*16+kk];
      gd  += (double)Pd [t*16+j] * (double)Pd [t*16+kk];
      g0  += (double)P  [t*16+j] * (double)P  [t*16+kk];
    }
    const double cs = 100.0 * (gdd + ((j == kk) ? 0.1 : 0.0));
    const double g  = gdd + gd + (isY ? 12.0 : 10.0) * g0;
    G[j][kk] = g;
    C[j][kk] = (mid >= 2) ? (cs + g) : cs;
  }
  if (tid < 16) {
    const int j = tid;
    Ae[0][j] = (double)P  [0*16+j];
    Ae[1][j] = (double)Pd [0*16+j];
    Ae[2][j] = (double)Pdd[0*16+j];
    if (!isY) {
      Ae[3][j] = (double)Pd[127*16+j];
      for (int r = 4; r < 8; ++r) Ae[r][j] = (j == r) ? 1.0 : 0.0;
    } else {
      Ae[3][j] = (double)P [127*16+j];
      Ae[4][j] = (double)Pd[127*16+j];
      for (int r = 5; r < 9; ++r) Ae[r][j] = (j == (r-1)) ? 1.0 : 0.0;
    }
  }
  __syncthreads();

  for (int e = tid; e < n * w; e += 64) {
    const int r = e / w, c = e % w;
    double val;
    if (c < n) {
      if (r < 16) val = (c < 16) ? C[r][c] : Ae[c-16][r];
      else        val = (c < 16) ? Ae[r-16][c] : 0.0;
    } else {
      val = ((c - n) == r) ? 1.0 : 0.0;
    }
    aug[r][c] = val;
  }
  __syncthreads();

  // Gauss-Jordan with partial pivoting (wave-parallel)
  const int hw  = (w + 1) >> 1;       // half-row width
  const int rw  = tid >> 1;           // row handled by this lane (2 lanes/row)
  const int hf  = tid & 1;
  for (int kk = 0; kk < n; ++kk) {
    // parallel argmax pivot over rows kk..n-1 (smallest index on ties)
    {
      double a = (tid >= kk && tid < n) ? fabs(aug[tid][kk]) : -1.0;
      int p = tid;
      #pragma unroll
      for (int off = 1; off < 64; off <<= 1) {
        const double oa = __shfl_xor(a, off);
        const int    op = __shfl_xor(p, off);
        if (oa > a || (oa == a && op < p)) { a = oa; p = op; }
      }
      if (tid == 0) pivs = p;
    }
    __syncthreads();
    const int p = pivs;
    if (p != kk) {
      for (int c = tid; c < w; c += 64) { double t = aug[kk][c]; aug[kk][c] = aug[p][c]; aug[p][c] = t; }
    }
    __syncthreads();
    const double ipiv = 1.0 / aug[kk][kk];
    for (int c = tid; c < w; c += 64) aug[kk][c] *= ipiv;
    if (tid < n) fcol[tid] = aug[tid][kk];   // fcol[kk] races with scale but is unused
    __syncthreads();
    if (rw < n && rw != kk) {
      const double f = fcol[rw];
      const int c0 = hf * hw;
      const int c1 = (c0 + hw < w) ? (c0 + hw) : w;
      for (int c = c0; c < c1; ++c) aug[rw][c] -= f * aug[kk][c];
    }
    __syncthreads();
  }

  if (mid == 0) {
    for (int e = tid; e < 16*8; e += 64) ws[WS_NX0 + e] = (float)aug[e >> 3][n + 16 + (e & 7)];
  } else if (mid == 1) {
    for (int e = tid; e < 16*9; e += 64) ws[WS_NY0 + e] = (float)aug[e / 9][n + 16 + (e % 9)];
  } else if (mid == 2) {
    for (int e = tid; e < 256;  e += 64) ws[WS_MX + e] = (float)aug[e >> 4][n + (e & 15)];
    for (int e = tid; e < 16*8; e += 64) ws[WS_NX + e] = (float)aug[e >> 3][n + 16 + (e & 7)];
  } else {
    for (int e = tid; e < 256;  e += 64) ws[WS_MY + e] = (float)aug[e >> 4][n + (e & 15)];
    for (int e = tid; e < 16*9; e += 64) ws[WS_NY + e] = (float)aug[e / 9][n + 16 + (e % 9)];
  }

  if (mid >= 2) {
    for (int e = tid; e < 256; e += 64) {
      const int j = e >> 4, kk = e & 15;
      double s = 0.0;
      for (int mm = 0; mm < 16; ++mm) s += aug[j][n + mm] * G[mm][kk];
      ws[(mid == 2 ? WS_MGX : WS_MGY) + e] = (float)s;
    }
  }
}

// ---- main kernel: ONE wave (64 threads) per problem, 2 timesteps/thread ----
// Obstacle trajectories live in LDS (not registers) to keep VGPR <= 128.
__global__ __launch_bounds__(64) void planner_main(
    const float* __restrict__ P, const float* __restrict__ Pd, const float* __restrict__ Pdd,
    const float* __restrict__ init_state, const float* __restrict__ fin_state,
    const float* __restrict__ cobs, const float* __restrict__ vobs,
    const float* __restrict__ yub_g, const float* __restrict__ ylb_g,
    const float* __restrict__ lamx_g, const float* __restrict__ lamy_g,
    const float* __restrict__ cxp_g, const float* __restrict__ cyp_g,
    const float* __restrict__ ws, float* __restrict__ out)
{
  const int b    = blockIdx.x;
  const int tid  = threadIdx.x;        // timesteps t0 = tid, t1 = tid + 64
  const int o32  = tid & 31;           // reduction row owned (dup over cc)
  const int cc   = tid >> 5;
  const int rr   = tid & 15;           // solve row
  const int side = (tid >> 4) & 1;     // 0 = x-side, 1 = y-side
  const int q4   = tid >> 2;           // quad index (0..15)
  const int k    = tid & 3;            // lane-in-quad

  __shared__ alignas(16) float red[16*RS];        // [quad][o], 2.3 KB
  __shared__ alignas(16) float obsL[2][5][64*4];  // 10.2 KB: {xot.x,xot.y,yot.x,yot.y}
  __shared__ alignas(16) float cL[32];
  __shared__ alignas(16) float hL[32];

  // basis rows for both timesteps (j-pair packed) -- 96 VGPRs, the main state
  f32x2 Pr2[2][8], Pdr2[2][8], Pddr2[2][8];
  #pragma unroll
  for (int u = 0; u < 2; ++u) {
    const int t = tid + 64*u;
    #pragma unroll
    for (int q = 0; q < 4; ++q) {
      F4 a, bb, ce;
      a.v  = *reinterpret_cast<const float4*>(P   + t*16 + 4*q);
      bb.v = *reinterpret_cast<const float4*>(Pd  + t*16 + 4*q);
      ce.v = *reinterpret_cast<const float4*>(Pdd + t*16 + 4*q);
      Pr2  [u][2*q+0] = f32x2{a.f[0],  a.f[1]};  Pr2  [u][2*q+1] = f32x2{a.f[2],  a.f[3]};
      Pdr2 [u][2*q+0] = f32x2{bb.f[0], bb.f[1]}; Pdr2 [u][2*q+1] = f32x2{bb.f[2], bb.f[3]};
      Pddr2[u][2*q+0] = f32x2{ce.f[0], ce.f[1]}; Pddr2[u][2*q+1] = f32x2{ce.f[2], ce.f[3]};
    }
  }

  // pre-scaled obstacle trajectories -> LDS (written once, read every iter)
  {
    const float tt0 = (float)tid        * (10.0f/127.0f);
    const float tt1 = (float)(tid + 64) * (10.0f/127.0f);
    #pragma unroll
    for (int o5 = 0; o5 < 5; ++o5) {
      const int o = 2*o5;
      const float xo0 = cobs[b*20+o],    xo1 = cobs[b*20+o+1];
      const float yo0 = cobs[b*20+10+o], yo1 = cobs[b*20+11+o];
      const float vx0 = vobs[b*20+o],    vx1 = vobs[b*20+o+1];
      const float vy0 = vobs[b*20+10+o], vy1 = vobs[b*20+11+o];
      *reinterpret_cast<float4*>(&obsL[0][o5][tid*4]) =
          float4{3.2f*fmaf(vx0,tt0,xo0), 3.2f*fmaf(vx1,tt0,xo1),
                 6.0f*fmaf(vy0,tt0,yo0), 6.0f*fmaf(vy1,tt0,yo1)};
      *reinterpret_cast<float4*>(&obsL[1][o5][tid*4]) =
          float4{3.2f*fmaf(vx0,tt1,xo0), 3.2f*fmaf(vx1,tt1,xo1),
                 6.0f*fmaf(vy0,tt1,yo0), 6.0f*fmaf(vy1,tt1,yo1)};
    }
  }
  const float yub = yub_g[b], ylb = ylb_g[b];

  // lambda carry for owned reduction row (dup across cc)
  float lam = (o32 < 16) ? lamx_g[b*16 + o32] : lamy_g[b*16 + (o32 - 16)];

  // per-lane solve-row setup: const term, initial c (row rr, side)
  float constv, myc;
  {
    float beq[9];
    const float vi  = init_state[b*4+2];
    const float psi = init_state[b*4+3];
    if (side == 0) {
      beq[0] = init_state[b*4+0];
      beq[1] = vi * cosf(psi);
      beq[2] = 0.f;
      beq[3] = fin_state[b*3+0];
      #pragma unroll
      for (int i2 = 0; i2 < 4; ++i2) beq[4+i2] = cxp_g[b*4+i2];
      beq[8] = 0.f;                      // pad: multiplies in-bounds junk * 0
    } else {
      beq[0] = init_state[b*4+1];
      beq[1] = vi * sinf(psi);
      beq[2] = 0.f;
      beq[3] = fin_state[b*3+1];
      beq[4] = 0.f;
      #pragma unroll
      for (int i2 = 0; i2 < 4; ++i2) beq[5+i2] = cyp_g[b*4+i2];
    }
    const int nstr = side ? 9 : 8;
    const float* Np  = ws + (side ? WS_NY  : WS_NX ) + rr*nstr;
    const float* N0p = ws + (side ? WS_NY0 : WS_NX0) + rr*nstr;
    float cv = 0.f, c0 = 0.f;
    #pragma unroll
    for (int mm = 0; mm < 9; ++mm) {
      const float bm = beq[mm];
      cv = fmaf(Np[mm],  bm, cv);
      c0 = fmaf(N0p[mm], bm, c0);
    }
    constv = cv;
    myc    = c0;
  }
  if (tid < 32) cL[tid] = myc;           // same-wave DS ordering

  const float* Mrow  = ws + (side ? WS_MY  : WS_MX ) + rr*16;
  const float* MGrow = ws + (side ? WS_MGY : WS_MGX) + rr*16;
  const bool  kb2 = (k & 2) != 0;
  const int   k1  = k & 1;

  #pragma unroll 1
  for (int it = 0; it < MAXIT; ++it) {
    __builtin_amdgcn_wave_barrier();
    // ---- forward matvecs, t0 then t1 (6 packed accumulators reused) ----
    float x0,y0,xd0,yd0,xdd0,ydd0, x1,y1,xd1,yd1,xdd1,ydd1;
    #pragma unroll
    for (int u = 0; u < 2; ++u) {
      f32x2 xv{},yv{},xdv{},ydv{},xddv{},yddv{};
      #pragma unroll
      for (int q = 0; q < 4; ++q) {
        F4 cx4, cy4;
        cx4.v = *reinterpret_cast<const float4*>(&cL[4*q]);
        cy4.v = *reinterpret_cast<const float4*>(&cL[16 + 4*q]);
        const f32x2 c01 = f32x2{cx4.f[0], cx4.f[1]}, c23 = f32x2{cx4.f[2], cx4.f[3]};
        const f32x2 d01 = f32x2{cy4.f[0], cy4.f[1]}, d23 = f32x2{cy4.f[2], cy4.f[3]};
        xv   = pfma(Pr2  [u][2*q], c01, xv);   xv   = pfma(Pr2  [u][2*q+1], c23, xv);
        yv   = pfma(Pr2  [u][2*q], d01, yv);   yv   = pfma(Pr2  [u][2*q+1], d23, yv);
        xdv  = pfma(Pdr2 [u][2*q], c01, xdv);  xdv  = pfma(Pdr2 [u][2*q+1], c23, xdv);
        ydv  = pfma(Pdr2 [u][2*q], d01, ydv);  ydv  = pfma(Pdr2 [u][2*q+1], d23, ydv);
        xddv = pfma(Pddr2[u][2*q], c01, xddv); xddv = pfma(Pddr2[u][2*q+1], c23, xddv);
        yddv = pfma(Pddr2[u][2*q], d01, yddv); yddv = pfma(Pddr2[u][2*q+1], d23, yddv);
      }
      if (u == 0) {
        x0=xv.x+xv.y; y0=yv.x+yv.y; xd0=xdv.x+xdv.y; yd0=ydv.x+ydv.y;
        xdd0=xddv.x+xddv.y; ydd0=yddv.x+yddv.y;
      } else {
        x1=xv.x+xv.y; y1=yv.x+yv.y; xd1=xdv.x+xdv.y; yd1=ydv.x+ydv.y;
        xdd1=xddv.x+xddv.y; ydd1=yddv.x+yddv.y;
      }
    }

    // ---- projections ----
    const float ria0 = rsqrtf(fmaxf(fmaf(xdd0,xdd0,ydd0*ydd0), 1e-36f));
    const float ga10 = 1.0f - fminf(1.0f, 18.0f*ria0);
    const float riv0 = rsqrtf(fmaxf(fmaf(xd0,xd0,yd0*yd0), 1e-36f));
    const float gv10 = 1.0f - fminf(fmaxf(1.0f, 0.1f*riv0), 30.0f*riv0);
    const float ria1 = rsqrtf(fmaxf(fmaf(xdd1,xdd1,ydd1*ydd1), 1e-36f));
    const float ga11 = 1.0f - fminf(1.0f, 18.0f*ria1);
    const float riv1 = rsqrtf(fmaxf(fmaf(xd1,xd1,yd1*yd1), 1e-36f));
    const float gv11 = 1.0f - fminf(fmaxf(1.0f, 0.1f*riv1), 30.0f*riv1);

    // ---- obstacles (trajectories read back from LDS) ----
    f32x2 Sx0{}, Sy0{}, Sx1{}, Sy1{};
    {
      const f32x2 xb0 = f32x2{3.2f*x0, 3.2f*x0}, yb0 = f32x2{6.0f*y0, 6.0f*y0};
      const f32x2 xb1 = f32x2{3.2f*x1, 3.2f*x1}, yb1 = f32x2{6.0f*y1, 6.0f*y1};
      #pragma unroll
      for (int o5 = 0; o5 < 5; ++o5) {
        F4 ob0, ob1;
        ob0.v = *reinterpret_cast<const float4*>(&obsL[0][o5][tid*4]);
        ob1.v = *reinterpret_cast<const float4*>(&obsL[1][o5][tid*4]);
        const f32x2 bw0 = xb0 - f32x2{ob0.f[0], ob0.f[1]};
        const f32x2 aw0 = yb0 - f32x2{ob0.f[2], ob0.f[3]};
        const f32x2 bw1 = xb1 - f32x2{ob1.f[0], ob1.f[1]};
        const f32x2 aw1 = yb1 - f32x2{ob1.f[2], ob1.f[3]};
        const f32x2 r20 = pfma(bw0,bw0,aw0*aw0);
        const f32x2 r21 = pfma(bw1,bw1,aw1*aw1);
        const f32x2 ee0 = f32x2{
          fmaxf(fmaf(19.2f, rsqrtf(fmaxf(r20.x,1e-36f)), -1.0f), 0.f),
          fmaxf(fmaf(19.2f, rsqrtf(fmaxf(r20.y,1e-36f)), -1.0f), 0.f)};
        const f32x2 ee1 = f32x2{
          fmaxf(fmaf(19.2f, rsqrtf(fmaxf(r21.x,1e-36f)), -1.0f), 0.f),
          fmaxf(fmaf(19.2f, rsqrtf(fmaxf(r21.y,1e-36f)), -1.0f), 0.f)};
        Sx0 = pfma(ee0, bw0, Sx0);  Sy0 = pfma(ee0, aw0, Sy0);
        Sx1 = pfma(ee1, bw1, Sx1);  Sy1 = pfma(ee1, aw1, Sy1);
      }
    }
    const float c0p0 = -(Sx0.x+Sx0.y)*0.3125f;
    const float rln0 = fmaxf(y0-yub,0.f) - fmaxf(ylb-y0,0.f);
    const float c2p0 = rln0 - (Sy0.x+Sy0.y)*(1.0f/6.0f);
    const float c0dd0 = xdd0*ga10, c0d0 = xd0*gv10;
    const float c2dd0 = ydd0*ga10, c2d0 = yd0*gv10;
    const float c0p1 = -(Sx1.x+Sx1.y)*0.3125f;
    const float rln1 = fmaxf(y1-yub,0.f) - fmaxf(ylb-y1,0.f);
    const float c2p1 = rln1 - (Sy1.x+Sy1.y)*(1.0f/6.0f);
    const float c0dd1 = xdd1*ga11, c0d1 = xd1*gv11;
    const float c2dd1 = ydd1*ga11, c2d1 = yd1*gv11;

    // ---- back-projection (pre-summed over own 2 t's) + quad DPP reduce ----
    float outv[8];
    #pragma unroll
    for (int s2 = 0; s2 < 8; ++s2) outv[s2] = 0.f;
    {
      const f32x2 A00{c0dd0,c0dd0}, D00{c0d0,c0d0}, Q00{c0p0,c0p0};
      const f32x2 A20{c2dd0,c2dd0}, D20{c2d0,c2d0}, Q20{c2p0,c2p0};
      const f32x2 A01{c0dd1,c0dd1}, D01{c0d1,c0d1}, Q01{c0p1,c0p1};
      const f32x2 A21{c2dd1,c2dd1}, D21{c2d1,c2d1}, Q21{c2p1,c2p1};
      #pragma unroll
      for (int j2 = 0; j2 < 8; ++j2) {
        f32x2 vx = pfma(A00, Pddr2[0][j2], pfma(D00, Pdr2[0][j2], Q00*Pr2[0][j2]));
        vx = pfma(A01, Pddr2[1][j2], pfma(D01, Pdr2[1][j2], pfma(Q01, Pr2[1][j2], vx)));
        f32x2 vy = pfma(A20, Pddr2[0][j2], pfma(D20, Pdr2[0][j2], Q20*Pr2[0][j2]));
        vy = pfma(A21, Pddr2[1][j2], pfma(D21, Pdr2[1][j2], pfma(Q21, Pr2[1][j2], vy)));
        // quad sums (each covers 8 timesteps)
        const float qx0 = qsum(vx.x), qx1 = qsum(vx.y);
        const float qy0 = qsum(vy.x), qy1 = qsum(vy.y);
        // lane k of each quad keeps o-chunk [8k, 8k+8)
        const float s0 = kb2 ? qy0 : qx0;
        const float s1 = kb2 ? qy1 : qx1;
        const bool match = (k1 == (j2 >> 2));
        const int  sb = 2*(j2 & 3);
        outv[sb]   = match ? s0 : outv[sb];
        outv[sb+1] = match ? s1 : outv[sb+1];
      }
    }
    __builtin_amdgcn_wave_barrier();
    {
      float* wr = red + q4*RS + 8*k;
      *reinterpret_cast<float4*>(wr)     = float4{outv[0],outv[1],outv[2],outv[3]};
      *reinterpret_cast<float4*>(wr + 4) = float4{outv[4],outv[5],outv[6],outv[7]};
    }
    __builtin_amdgcn_wave_barrier();

    // ---- reduce 16 quad-rows for owned column o32 ----
    float h;
    {
      const float* rd = red + (cc*8)*RS + o32;
      float s = 0.f;
      #pragma unroll
      for (int i = 0; i < 8; ++i) s += rd[i*RS];
      s += __shfl_xor(s, 32);
      lam -= s;
      h = lam - s;                         // lam_old - 2S
    }
    __builtin_amdgcn_wave_barrier();
    if (tid < 32) hL[tid] = h;
    __builtin_amdgcn_wave_barrier();

    // ---- fused solve: c' = MG*c + M*h + const ----
    {
      f32x2 accv{};
      #pragma unroll
      for (int q = 0; q < 4; ++q) {
        F4 m4, g4, h4, c4;
        m4.v = *reinterpret_cast<const float4*>(Mrow  + 4*q);
        g4.v = *reinterpret_cast<const float4*>(MGrow + 4*q);
        h4.v = *reinterpret_cast<const float4*>(&hL[side*16 + 4*q]);
        c4.v = *reinterpret_cast<const float4*>(&cL[side*16 + 4*q]);
        accv = pfma(f32x2{m4.f[0],m4.f[1]}, f32x2{h4.f[0],h4.f[1]}, accv);
        accv = pfma(f32x2{g4.f[0],g4.f[1]}, f32x2{c4.f[0],c4.f[1]}, accv);
        accv = pfma(f32x2{m4.f[2],m4.f[3]}, f32x2{h4.f[2],h4.f[3]}, accv);
        accv = pfma(f32x2{g4.f[2],g4.f[3]}, f32x2{c4.f[2],c4.f[3]}, accv);
      }
      myc = constv + accv.x + accv.y;
    }
    __builtin_amdgcn_wave_barrier();
    if (tid < 32) cL[tid] = myc;           // next iter reads (same-wave order)
  }

  if (tid < 32) out[b*32 + tid] = myc;
}

extern "C" void kernel_launch(void* const* d_in, const int* in_sizes, int n_in,
                              void* d_out, int out_size, void* d_ws, size_t ws_size,
                              hipStream_t stream) {
  const float* P    = (const float*)d_in[0];
  const float* Pd   = (const float*)d_in[1];
  const float* Pdd  = (const float*)d_in[2];
  const float* init = (const float*)d_in[3];
  const float* fin  = (const float*)d_in[4];
  const float* cobs = (const float*)d_in[5];
  const float* vobs = (const float*)d_in[6];
  const float* yub  = (const float*)d_in[7];
  const float* ylb  = (const float*)d_in[8];
  const float* lamx = (const float*)d_in[9];
  const float* lamy = (const float*)d_in[10];
  const float* cxp  = (const float*)d_in[11];
  const float* cyp  = (const float*)d_in[12];
  float* ws  = (float*)d_ws;
  float* o   = (float*)d_out;

  planner_setup<<<dim3(4), dim3(64), 0, stream>>>(P, Pd, Pdd, ws);
  planner_main<<<dim3(NBATCH), dim3(64), 0, stream>>>(
      P, Pd, Pdd, init, fin, cobs, vobs, yub, ylb, lamx, lamy, cxp, cyp, ws, o);
}

// Round 13
// 211.937 us; speedup vs baseline: 4.2937x; 1.0321x over previous
//
#include <hip/hip_runtime.h>
#include <math.h>

#define NBATCH 4096
#define TNUM   128
#define NOBSC  10
#define MAXIT  30

// ws layout (floats)
#define WS_MX   0      // 16x16
#define WS_MY   256    // 16x16
#define WS_MGX  512    // 16x16  (Mx*Gx)
#define WS_MGY  768    // 16x16  (My*Gy)
#define WS_NX   1024   // 16x8
#define WS_NY   1152   // 16x9
#define WS_NX0  1296   // 16x8
#define WS_NY0  1424   // 16x9
// total 1568 floats

#define RS 36          // red row stride (16 quad-rows x 32 cols + pad)

typedef float f32x2 __attribute__((ext_vector_type(2)));
union F4 { float4 v; float f[4]; };
union F2 { float2 v; float f[2]; };

__device__ __forceinline__ f32x2 pfma(f32x2 a, f32x2 b, f32x2 c) {
  return __builtin_elementwise_fma(a, b, c);
}

// quad-lane (4 consecutive lanes) all-reduce sum via DPP (VALU pipe, no LDS)
__device__ __forceinline__ float qsum(float v) {
  float s = v + __int_as_float(__builtin_amdgcn_update_dpp(
      0, __float_as_int(v), 0xB1, 0xF, 0xF, true));   // quad_perm [1,0,3,2] = xor1
  s = s + __int_as_float(__builtin_amdgcn_update_dpp(
      0, __float_as_int(s), 0x4E, 0xF, 0xF, true));   // quad_perm [2,3,0,1] = xor2
  return s;
}

// ---------------- setup kernel: build + invert KKT matrices (fp64 GJ) -------
__global__ __launch_bounds__(64) void planner_setup(
    const float* __restrict__ P, const float* __restrict__ Pd, const float* __restrict__ Pdd,
    float* __restrict__ ws)
{
  const int mid = blockIdx.x;   // 0: (cost_sm,Ax)->Nx0  1: (cost_sm,Ay)->Ny0
                                // 2: (cost_x,Ax)->Mx,Nx,MGx 3: (cost_y,Ay)->My,Ny,MGy
  const int tid = threadIdx.x;
  __shared__ float Af[3][TNUM*16];   // staged P, Pd, Pdd (24 KB)
  __shared__ double C[16][16];
  __shared__ double G[16][16];
  __shared__ double Ae[9][16];
  __shared__ double aug[25][50];
  __shared__ double fcol[32];
  __shared__ int pivs;

  const bool isY = (mid & 1);
  const int  m   = isY ? 9 : 8;
  const int  n   = 16 + m;
  const int  w   = 2 * n;

  // stage basis matrices into LDS (coalesced b128 loads)
  #pragma unroll
  for (int u = 0; u < 2; ++u) {
    const int t = tid + 64*u;
    #pragma unroll
    for (int q = 0; q < 4; ++q) {
      *reinterpret_cast<float4*>(&Af[0][t*16+4*q]) = *reinterpret_cast<const float4*>(P   + t*16 + 4*q);
      *reinterpret_cast<float4*>(&Af[1][t*16+4*q]) = *reinterpret_cast<const float4*>(Pd  + t*16 + 4*q);
      *reinterpret_cast<float4*>(&Af[2][t*16+4*q]) = *reinterpret_cast<const float4*>(Pdd + t*16 + 4*q);
    }
  }
  __syncthreads();

  // Gram matrices: each lane owns a 2x2 entry tile (8x8 grid of tiles)
  {
    const int j0 = (tid >> 3) * 2;
    const int k0 = (tid & 7) * 2;
    double acc[3][2][2];
    #pragma unroll
    for (int mm = 0; mm < 3; ++mm)
      #pragma unroll
      for (int a2 = 0; a2 < 2; ++a2)
        #pragma unroll
        for (int b2 = 0; b2 < 2; ++b2) acc[mm][a2][b2] = 0.0;
    for (int t = 0; t < TNUM; ++t) {
      #pragma unroll
      for (int mm = 0; mm < 3; ++mm) {
        F2 aj, ak;
        aj.v = *reinterpret_cast<const float2*>(&Af[mm][t*16 + j0]);
        ak.v = *reinterpret_cast<const float2*>(&Af[mm][t*16 + k0]);
        #pragma unroll
        for (int a2 = 0; a2 < 2; ++a2)
          #pragma unroll
          for (int b2 = 0; b2 < 2; ++b2)
            acc[mm][a2][b2] += (double)aj.f[a2] * (double)ak.f[b2];
      }
    }
    const double wsc = isY ? 12.0 : 10.0;
    #pragma unroll
    for (int a2 = 0; a2 < 2; ++a2) {
      #pragma unroll
      for (int b2 = 0; b2 < 2; ++b2) {
        const int j = j0 + a2, kk = k0 + b2;
        const double gdd = acc[2][a2][b2], gd = acc[1][a2][b2], g0 = acc[0][a2][b2];
        const double cs = 100.0 * (gdd + ((j == kk) ? 0.1 : 0.0));
        const double g  = gdd + gd + wsc * g0;
        G[j][kk] = g;
        C[j][kk] = (mid >= 2) ? (cs + g) : cs;
      }
    }
  }
  if (tid < 16) {
    const int j = tid;
    Ae[0][j] = (double)P  [0*16+j];
    Ae[1][j] = (double)Pd [0*16+j];
    Ae[2][j] = (double)Pdd[0*16+j];
    if (!isY) {
      Ae[3][j] = (double)Pd[127*16+j];
      for (int r = 4; r < 8; ++r) Ae[r][j] = (j == r) ? 1.0 : 0.0;
    } else {
      Ae[3][j] = (double)P [127*16+j];
      Ae[4][j] = (double)Pd[127*16+j];
      for (int r = 5; r < 9; ++r) Ae[r][j] = (j == (r-1)) ? 1.0 : 0.0;
    }
  }
  __syncthreads();

  for (int e = tid; e < n * w; e += 64) {
    const int r = e / w, c = e % w;
    double val;
    if (c < n) {
      if (r < 16) val = (c < 16) ? C[r][c] : Ae[c-16][r];
      else        val = (c < 16) ? Ae[r-16][c] : 0.0;
    } else {
      val = ((c - n) == r) ? 1.0 : 0.0;
    }
    aug[r][c] = val;
  }
  __syncthreads();

  // Gauss-Jordan with partial pivoting (wave-parallel)
  const int hw  = (w + 1) >> 1;       // half-row width
  const int rw  = tid >> 1;           // row handled by this lane (2 lanes/row)
  const int hf  = tid & 1;
  for (int kk = 0; kk < n; ++kk) {
    // parallel argmax pivot over rows kk..n-1 (smallest index on ties)
    {
      double a = (tid >= kk && tid < n) ? fabs(aug[tid][kk]) : -1.0;
      int p = tid;
      #pragma unroll
      for (int off = 1; off < 64; off <<= 1) {
        const double oa = __shfl_xor(a, off);
        const int    op = __shfl_xor(p, off);
        if (oa > a || (oa == a && op < p)) { a = oa; p = op; }
      }
      if (tid == 0) pivs = p;
    }
    __syncthreads();
    const int p = pivs;
    if (p != kk) {
      for (int c = tid; c < w; c += 64) { double t = aug[kk][c]; aug[kk][c] = aug[p][c]; aug[p][c] = t; }
    }
    __syncthreads();
    const double ipiv = 1.0 / aug[kk][kk];
    for (int c = tid; c < w; c += 64) aug[kk][c] *= ipiv;
    if (tid < n) fcol[tid] = aug[tid][kk];   // fcol[kk] races with scale but is unused
    __syncthreads();
    if (rw < n && rw != kk) {
      const double f = fcol[rw];
      const int c0 = hf * hw;
      const int c1 = (c0 + hw < w) ? (c0 + hw) : w;
      for (int c = c0; c < c1; ++c) aug[rw][c] -= f * aug[kk][c];
    }
    __syncthreads();
  }

  if (mid == 0) {
    for (int e = tid; e < 16*8; e += 64) ws[WS_NX0 + e] = (float)aug[e >> 3][n + 16 + (e & 7)];
  } else if (mid == 1) {
    for (int e = tid; e < 16*9; e += 64) ws[WS_NY0 + e] = (float)aug[e / 9][n + 16 + (e % 9)];
  } else if (mid == 2) {
    for (int e = tid; e < 256;  e += 64) ws[WS_MX + e] = (float)aug[e >> 4][n + (e & 15)];
    for (int e = tid; e < 16*8; e += 64) ws[WS_NX + e] = (float)aug[e >> 3][n + 16 + (e & 7)];
  } else {
    for (int e = tid; e < 256;  e += 64) ws[WS_MY + e] = (float)aug[e >> 4][n + (e & 15)];
    for (int e = tid; e < 16*9; e += 64) ws[WS_NY + e] = (float)aug[e / 9][n + 16 + (e % 9)];
  }

  if (mid >= 2) {
    for (int e = tid; e < 256; e += 64) {
      const int j = e >> 4, kk = e & 15;
      double s = 0.0;
      for (int mm = 0; mm < 16; ++mm) s += aug[j][n + mm] * G[mm][kk];
      ws[(mid == 2 ? WS_MGX : WS_MGY) + e] = (float)s;
    }
  }
}

// ---- main kernel: ONE wave (64 threads) per problem, 2 timesteps/thread ----
// LDS <= 8 KB so all 16 blocks/CU are co-resident (grid = 16 blocks/CU exactly).
__global__ __launch_bounds__(64) void planner_main(
    const float* __restrict__ P, const float* __restrict__ Pd, const float* __restrict__ Pdd,
    const float* __restrict__ init_state, const float* __restrict__ fin_state,
    const float* __restrict__ cobs, const float* __restrict__ vobs,
    const float* __restrict__ yub_g, const float* __restrict__ ylb_g,
    const float* __restrict__ lamx_g, const float* __restrict__ lamy_g,
    const float* __restrict__ cxp_g, const float* __restrict__ cyp_g,
    const float* __restrict__ ws, float* __restrict__ out)
{
  const int b    = blockIdx.x;
  const int tid  = threadIdx.x;        // timesteps t0 = tid, t1 = tid + 64
  const int o32  = tid & 31;           // reduction row owned (dup over cc)
  const int cc   = tid >> 5;
  const int rr   = tid & 15;           // solve row
  const int side = (tid >> 4) & 1;     // 0 = x-side, 1 = y-side
  const int q4   = tid >> 2;           // quad index (0..15)
  const int k    = tid & 3;            // lane-in-quad

  __shared__ alignas(16) float red[16*RS];      // [quad][o], 2.3 KB
  __shared__ alignas(16) float obsL0[5*64*4];   // 5.1 KB: t0 traj {x0,x1,y0,y1}
  __shared__ alignas(16) float dL[5*4];         // 80 B: uniform per-o delta
  __shared__ alignas(16) float cL[32];
  __shared__ alignas(16) float hL[32];

  // basis rows for both timesteps (j-pair packed) -- 96 VGPRs, the main state
  f32x2 Pr2[2][8], Pdr2[2][8], Pddr2[2][8];
  #pragma unroll
  for (int u = 0; u < 2; ++u) {
    const int t = tid + 64*u;
    #pragma unroll
    for (int q = 0; q < 4; ++q) {
      F4 a, bb, ce;
      a.v  = *reinterpret_cast<const float4*>(P   + t*16 + 4*q);
      bb.v = *reinterpret_cast<const float4*>(Pd  + t*16 + 4*q);
      ce.v = *reinterpret_cast<const float4*>(Pdd + t*16 + 4*q);
      Pr2  [u][2*q+0] = f32x2{a.f[0],  a.f[1]};  Pr2  [u][2*q+1] = f32x2{a.f[2],  a.f[3]};
      Pdr2 [u][2*q+0] = f32x2{bb.f[0], bb.f[1]}; Pdr2 [u][2*q+1] = f32x2{bb.f[2], bb.f[3]};
      Pddr2[u][2*q+0] = f32x2{ce.f[0], ce.f[1]}; Pddr2[u][2*q+1] = f32x2{ce.f[2], ce.f[3]};
    }
  }

  // pre-scaled obstacle trajectories at t0 -> LDS; uniform t1-t0 delta -> dL
  {
    const float tt0 = (float)tid * (10.0f/127.0f);
    #pragma unroll
    for (int o5 = 0; o5 < 5; ++o5) {
      const int o = 2*o5;
      *reinterpret_cast<float4*>(&obsL0[o5*256 + tid*4]) =
          float4{3.2f*fmaf(vobs[b*20+o],    tt0, cobs[b*20+o]),
                 3.2f*fmaf(vobs[b*20+o+1],  tt0, cobs[b*20+o+1]),
                 6.0f*fmaf(vobs[b*20+10+o], tt0, cobs[b*20+10+o]),
                 6.0f*fmaf(vobs[b*20+11+o], tt0, cobs[b*20+11+o])};
    }
    if (tid < 5) {
      const int o = 2*tid;
      const float dtt = 64.0f * (10.0f/127.0f);
      *reinterpret_cast<float4*>(&dL[tid*4]) =
          float4{3.2f*dtt*vobs[b*20+o],    3.2f*dtt*vobs[b*20+o+1],
                 6.0f*dtt*vobs[b*20+10+o], 6.0f*dtt*vobs[b*20+11+o]};
    }
  }
  const float yub = yub_g[b], ylb = ylb_g[b];

  // lambda carry for owned reduction row (dup across cc)
  float lam = (o32 < 16) ? lamx_g[b*16 + o32] : lamy_g[b*16 + (o32 - 16)];

  // per-lane solve-row setup: const term, initial c (row rr, side)
  float constv, myc;
  {
    float beq[9];
    const float vi  = init_state[b*4+2];
    const float psi = init_state[b*4+3];
    if (side == 0) {
      beq[0] = init_state[b*4+0];
      beq[1] = vi * cosf(psi);
      beq[2] = 0.f;
      beq[3] = fin_state[b*3+0];
      #pragma unroll
      for (int i2 = 0; i2 < 4; ++i2) beq[4+i2] = cxp_g[b*4+i2];
      beq[8] = 0.f;                      // pad: multiplies in-bounds junk * 0
    } else {
      beq[0] = init_state[b*4+1];
      beq[1] = vi * sinf(psi);
      beq[2] = 0.f;
      beq[3] = fin_state[b*3+1];
      beq[4] = 0.f;
      #pragma unroll
      for (int i2 = 0; i2 < 4; ++i2) beq[5+i2] = cyp_g[b*4+i2];
    }
    const int nstr = side ? 9 : 8;
    const float* Np  = ws + (side ? WS_NY  : WS_NX ) + rr*nstr;
    const float* N0p = ws + (side ? WS_NY0 : WS_NX0) + rr*nstr;
    float cv = 0.f, c0 = 0.f;
    #pragma unroll
    for (int mm = 0; mm < 9; ++mm) {
      const float bm = beq[mm];
      cv = fmaf(Np[mm],  bm, cv);
      c0 = fmaf(N0p[mm], bm, c0);
    }
    constv = cv;
    myc    = c0;
  }
  if (tid < 32) cL[tid] = myc;           // same-wave DS ordering

  const float* Mrow  = ws + (side ? WS_MY  : WS_MX ) + rr*16;
  const float* MGrow = ws + (side ? WS_MGY : WS_MGX) + rr*16;
  const bool  kb2 = (k & 2) != 0;
  const int   k1  = k & 1;

  #pragma unroll 1
  for (int it = 0; it < MAXIT; ++it) {
    __builtin_amdgcn_wave_barrier();
    // ---- forward matvecs, t0 then t1 (6 packed accumulators reused) ----
    float x0,y0,xd0,yd0,xdd0,ydd0, x1,y1,xd1,yd1,xdd1,ydd1;
    #pragma unroll
    for (int u = 0; u < 2; ++u) {
      f32x2 xv{},yv{},xdv{},ydv{},xddv{},yddv{};
      #pragma unroll
      for (int q = 0; q < 4; ++q) {
        F4 cx4, cy4;
        cx4.v = *reinterpret_cast<const float4*>(&cL[4*q]);
        cy4.v = *reinterpret_cast<const float4*>(&cL[16 + 4*q]);
        const f32x2 c01 = f32x2{cx4.f[0], cx4.f[1]}, c23 = f32x2{cx4.f[2], cx4.f[3]};
        const f32x2 d01 = f32x2{cy4.f[0], cy4.f[1]}, d23 = f32x2{cy4.f[2], cy4.f[3]};
        xv   = pfma(Pr2  [u][2*q], c01, xv);   xv   = pfma(Pr2  [u][2*q+1], c23, xv);
        yv   = pfma(Pr2  [u][2*q], d01, yv);   yv   = pfma(Pr2  [u][2*q+1], d23, yv);
        xdv  = pfma(Pdr2 [u][2*q], c01, xdv);  xdv  = pfma(Pdr2 [u][2*q+1], c23, xdv);
        ydv  = pfma(Pdr2 [u][2*q], d01, ydv);  ydv  = pfma(Pdr2 [u][2*q+1], d23, ydv);
        xddv = pfma(Pddr2[u][2*q], c01, xddv); xddv = pfma(Pddr2[u][2*q+1], c23, xddv);
        yddv = pfma(Pddr2[u][2*q], d01, yddv); yddv = pfma(Pddr2[u][2*q+1], d23, yddv);
      }
      if (u == 0) {
        x0=xv.x+xv.y; y0=yv.x+yv.y; xd0=xdv.x+xdv.y; yd0=ydv.x+ydv.y;
        xdd0=xddv.x+xddv.y; ydd0=yddv.x+yddv.y;
      } else {
        x1=xv.x+xv.y; y1=yv.x+yv.y; xd1=xdv.x+xdv.y; yd1=ydv.x+ydv.y;
        xdd1=xddv.x+xddv.y; ydd1=yddv.x+yddv.y;
      }
    }

    // ---- projections ----
    const float ria0 = rsqrtf(fmaxf(fmaf(xdd0,xdd0,ydd0*ydd0), 1e-36f));
    const float ga10 = 1.0f - fminf(1.0f, 18.0f*ria0);
    const float riv0 = rsqrtf(fmaxf(fmaf(xd0,xd0,yd0*yd0), 1e-36f));
    const float gv10 = 1.0f - fminf(fmaxf(1.0f, 0.1f*riv0), 30.0f*riv0);
    const float ria1 = rsqrtf(fmaxf(fmaf(xdd1,xdd1,ydd1*ydd1), 1e-36f));
    const float ga11 = 1.0f - fminf(1.0f, 18.0f*ria1);
    const float riv1 = rsqrtf(fmaxf(fmaf(xd1,xd1,yd1*yd1), 1e-36f));
    const float gv11 = 1.0f - fminf(fmaxf(1.0f, 0.1f*riv1), 30.0f*riv1);

    // ---- obstacles: t0 from LDS, t1 = t0 + uniform delta ----
    f32x2 Sx0{}, Sy0{}, Sx1{}, Sy1{};
    {
      const f32x2 xb0 = f32x2{3.2f*x0, 3.2f*x0}, yb0 = f32x2{6.0f*y0, 6.0f*y0};
      const f32x2 xb1 = f32x2{3.2f*x1, 3.2f*x1}, yb1 = f32x2{6.0f*y1, 6.0f*y1};
      #pragma unroll
      for (int o5 = 0; o5 < 5; ++o5) {
        F4 ob0, dd;
        ob0.v = *reinterpret_cast<const float4*>(&obsL0[o5*256 + tid*4]);
        dd.v  = *reinterpret_cast<const float4*>(&dL[o5*4]);
        const f32x2 obx = f32x2{ob0.f[0], ob0.f[1]};
        const f32x2 oby = f32x2{ob0.f[2], ob0.f[3]};
        const f32x2 bw0 = xb0 - obx;
        const f32x2 aw0 = yb0 - oby;
        const f32x2 bw1 = (xb1 - f32x2{dd.f[0], dd.f[1]}) - obx;
        const f32x2 aw1 = (yb1 - f32x2{dd.f[2], dd.f[3]}) - oby;
        const f32x2 r20 = pfma(bw0,bw0,aw0*aw0);
        const f32x2 r21 = pfma(bw1,bw1,aw1*aw1);
        const f32x2 ee0 = f32x2{
          fmaxf(fmaf(19.2f, rsqrtf(fmaxf(r20.x,1e-36f)), -1.0f), 0.f),
          fmaxf(fmaf(19.2f, rsqrtf(fmaxf(r20.y,1e-36f)), -1.0f), 0.f)};
        const f32x2 ee1 = f32x2{
          fmaxf(fmaf(19.2f, rsqrtf(fmaxf(r21.x,1e-36f)), -1.0f), 0.f),
          fmaxf(fmaf(19.2f, rsqrtf(fmaxf(r21.y,1e-36f)), -1.0f), 0.f)};
        Sx0 = pfma(ee0, bw0, Sx0);  Sy0 = pfma(ee0, aw0, Sy0);
        Sx1 = pfma(ee1, bw1, Sx1);  Sy1 = pfma(ee1, aw1, Sy1);
      }
    }
    const float c0p0 = -(Sx0.x+Sx0.y)*0.3125f;
    const float rln0 = fmaxf(y0-yub,0.f) - fmaxf(ylb-y0,0.f);
    const float c2p0 = rln0 - (Sy0.x+Sy0.y)*(1.0f/6.0f);
    const float c0dd0 = xdd0*ga10, c0d0 = xd0*gv10;
    const float c2dd0 = ydd0*ga10, c2d0 = yd0*gv10;
    const float c0p1 = -(Sx1.x+Sx1.y)*0.3125f;
    const float rln1 = fmaxf(y1-yub,0.f) - fmaxf(ylb-y1,0.f);
    const float c2p1 = rln1 - (Sy1.x+Sy1.y)*(1.0f/6.0f);
    const float c0dd1 = xdd1*ga11, c0d1 = xd1*gv11;
    const float c2dd1 = ydd1*ga11, c2d1 = yd1*gv11;

    // ---- back-projection (pre-summed over own 2 t's) + quad DPP reduce ----
    float outv[8];
    #pragma unroll
    for (int s2 = 0; s2 < 8; ++s2) outv[s2] = 0.f;
    {
      const f32x2 A00{c0dd0,c0dd0}, D00{c0d0,c0d0}, Q00{c0p0,c0p0};
      const f32x2 A20{c2dd0,c2dd0}, D20{c2d0,c2d0}, Q20{c2p0,c2p0};
      const f32x2 A01{c0dd1,c0dd1}, D01{c0d1,c0d1}, Q01{c0p1,c0p1};
      const f32x2 A21{c2dd1,c2dd1}, D21{c2d1,c2d1}, Q21{c2p1,c2p1};
      #pragma unroll
      for (int j2 = 0; j2 < 8; ++j2) {
        f32x2 vx = pfma(A00, Pddr2[0][j2], pfma(D00, Pdr2[0][j2], Q00*Pr2[0][j2]));
        vx = pfma(A01, Pddr2[1][j2], pfma(D01, Pdr2[1][j2], pfma(Q01, Pr2[1][j2], vx)));
        f32x2 vy = pfma(A20, Pddr2[0][j2], pfma(D20, Pdr2[0][j2], Q20*Pr2[0][j2]));
        vy = pfma(A21, Pddr2[1][j2], pfma(D21, Pdr2[1][j2], pfma(Q21, Pr2[1][j2], vy)));
        // quad sums (each covers 8 timesteps)
        const float qx0 = qsum(vx.x), qx1 = qsum(vx.y);
        const float qy0 = qsum(vy.x), qy1 = qsum(vy.y);
        // lane k of each quad keeps o-chunk [8k, 8k+8)
        const float s0 = kb2 ? qy0 : qx0;
        const float s1 = kb2 ? qy1 : qx1;
        const bool match = (k1 == (j2 >> 2));
        const int  sb = 2*(j2 & 3);
        outv[sb]   = match ? s0 : outv[sb];
        outv[sb+1] = match ? s1 : outv[sb+1];
      }
    }
    __builtin_amdgcn_wave_barrier();
    {
      float* wr = red + q4*RS + 8*k;
      *reinterpret_cast<float4*>(wr)     = float4{outv[0],outv[1],outv[2],outv[3]};
      *reinterpret_cast<float4*>(wr + 4) = float4{outv[4],outv[5],outv[6],outv[7]};
    }
    __builtin_amdgcn_wave_barrier();

    // ---- reduce 16 quad-rows for owned column o32 ----
    float h;
    {
      const float* rd = red + (cc*8)*RS + o32;
      float s = 0.f;
      #pragma unroll
      for (int i = 0; i < 8; ++i) s += rd[i*RS];
      s += __shfl_xor(s, 32);
      lam -= s;
      h = lam - s;                         // lam_old - 2S
    }
    __builtin_amdgcn_wave_barrier();
    if (tid < 32) hL[tid] = h;
    __builtin_amdgcn_wave_barrier();

    // ---- fused solve: c' = MG*c + M*h + const ----
    {
      f32x2 accv{};
      #pragma unroll
      for (int q = 0; q < 4; ++q) {
        F4 m4, g4, h4, c4;
        m4.v = *reinterpret_cast<const float4*>(Mrow  + 4*q);
        g4.v = *reinterpret_cast<const float4*>(MGrow + 4*q);
        h4.v = *reinterpret_cast<const float4*>(&hL[side*16 + 4*q]);
        c4.v = *reinterpret_cast<const float4*>(&cL[side*16 + 4*q]);
        accv = pfma(f32x2{m4.f[0],m4.f[1]}, f32x2{h4.f[0],h4.f[1]}, accv);
        accv = pfma(f32x2{g4.f[0],g4.f[1]}, f32x2{c4.f[0],c4.f[1]}, accv);
        accv = pfma(f32x2{m4.f[2],m4.f[3]}, f32x2{h4.f[2],h4.f[3]}, accv);
        accv = pfma(f32x2{g4.f[2],g4.f[3]}, f32x2{c4.f[2],c4.f[3]}, accv);
      }
      myc = constv + accv.x + accv.y;
    }
    __builtin_amdgcn_wave_barrier();
    if (tid < 32) cL[tid] = myc;           // next iter reads (same-wave order)
  }

  if (tid < 32) out[b*32 + tid] = myc;
}

extern "C" void kernel_launch(void* const* d_in, const int* in_sizes, int n_in,
                              void* d_out, int out_size, void* d_ws, size_t ws_size,
                              hipStream_t stream) {
  const float* P    = (const float*)d_in[0];
  const float* Pd   = (const float*)d_in[1];
  const float* Pdd  = (const float*)d_in[2];
  const float* init = (const float*)d_in[3];
  const float* fin  = (const float*)d_in[4];
  const float* cobs = (const float*)d_in[5];
  const float* vobs = (const float*)d_in[6];
  const float* yub  = (const float*)d_in[7];
  const float* ylb  = (const float*)d_in[8];
  const float* lamx = (const float*)d_in[9];
  const float* lamy = (const float*)d_in[10];
  const float* cxp  = (const float*)d_in[11];
  const float* cyp  = (const float*)d_in[12];
  float* ws  = (float*)d_ws;
  float* o   = (float*)d_out;

  planner_setup<<<dim3(4), dim3(64), 0, stream>>>(P, Pd, Pdd, ws);
  planner_main<<<dim3(NBATCH), dim3(64), 0, stream>>>(
      P, Pd, Pdd, init, fin, cobs, vobs, yub, ylb, lamx, lamy, cxp, cyp, ws, o);
}

// Round 14
// 209.228 us; speedup vs baseline: 4.3493x; 1.0129x over previous
//
#include <hip/hip_runtime.h>
#include <math.h>

#define NBATCH 4096
#define TNUM   128
#define NOBSC  10
#define MAXIT  30

// ws layout (floats)
#define WS_MX   0      // 16x16
#define WS_MY   256    // 16x16
#define WS_MGX  512    // 16x16  (Mx*Gx)
#define WS_MGY  768    // 16x16  (My*Gy)
#define WS_NX   1024   // 16x8
#define WS_NY   1152   // 16x9
#define WS_NX0  1296   // 16x8
#define WS_NY0  1424   // 16x9
// total 1568 floats

#define RS 36          // red row stride (16 quad-rows x 32 cols + pad)

typedef float f32x2 __attribute__((ext_vector_type(2)));
union F4 { float4 v; float f[4]; };
union F2 { float2 v; float f[2]; };

__device__ __forceinline__ f32x2 pfma(f32x2 a, f32x2 b, f32x2 c) {
  return __builtin_elementwise_fma(a, b, c);
}

// quad-lane (4 consecutive lanes) all-reduce sum via DPP (VALU pipe, no LDS)
__device__ __forceinline__ float qsum(float v) {
  float s = v + __int_as_float(__builtin_amdgcn_update_dpp(
      0, __float_as_int(v), 0xB1, 0xF, 0xF, true));   // quad_perm [1,0,3,2] = xor1
  s = s + __int_as_float(__builtin_amdgcn_update_dpp(
      0, __float_as_int(s), 0x4E, 0xF, 0xF, true));   // quad_perm [2,3,0,1] = xor2
  return s;
}

// ---------------- setup kernel: build + invert KKT matrices (fp64 GJ) -------
__global__ __launch_bounds__(64) void planner_setup(
    const float* __restrict__ P, const float* __restrict__ Pd, const float* __restrict__ Pdd,
    float* __restrict__ ws)
{
  const int mid = blockIdx.x;   // 0: (cost_sm,Ax)->Nx0  1: (cost_sm,Ay)->Ny0
                                // 2: (cost_x,Ax)->Mx,Nx,MGx 3: (cost_y,Ay)->My,Ny,MGy
  const int tid = threadIdx.x;
  __shared__ float Af[3][TNUM*16];   // staged P, Pd, Pdd (24 KB)
  __shared__ double C[16][16];
  __shared__ double G[16][16];
  __shared__ double Ae[9][16];
  __shared__ double aug[25][50];
  __shared__ double fcol[32];
  __shared__ int pivs;

  const bool isY = (mid & 1);
  const int  m   = isY ? 9 : 8;
  const int  n   = 16 + m;
  const int  w   = 2 * n;

  // stage basis matrices into LDS (coalesced b128 loads)
  #pragma unroll
  for (int u = 0; u < 2; ++u) {
    const int t = tid + 64*u;
    #pragma unroll
    for (int q = 0; q < 4; ++q) {
      *reinterpret_cast<float4*>(&Af[0][t*16+4*q]) = *reinterpret_cast<const float4*>(P   + t*16 + 4*q);
      *reinterpret_cast<float4*>(&Af[1][t*16+4*q]) = *reinterpret_cast<const float4*>(Pd  + t*16 + 4*q);
      *reinterpret_cast<float4*>(&Af[2][t*16+4*q]) = *reinterpret_cast<const float4*>(Pdd + t*16 + 4*q);
    }
  }
  __syncthreads();

  // Gram matrices: each lane owns a 2x2 entry tile (8x8 grid of tiles)
  {
    const int j0 = (tid >> 3) * 2;
    const int k0 = (tid & 7) * 2;
    double acc[3][2][2];
    #pragma unroll
    for (int mm = 0; mm < 3; ++mm)
      #pragma unroll
      for (int a2 = 0; a2 < 2; ++a2)
        #pragma unroll
        for (int b2 = 0; b2 < 2; ++b2) acc[mm][a2][b2] = 0.0;
    for (int t = 0; t < TNUM; ++t) {
      #pragma unroll
      for (int mm = 0; mm < 3; ++mm) {
        F2 aj, ak;
        aj.v = *reinterpret_cast<const float2*>(&Af[mm][t*16 + j0]);
        ak.v = *reinterpret_cast<const float2*>(&Af[mm][t*16 + k0]);
        #pragma unroll
        for (int a2 = 0; a2 < 2; ++a2)
          #pragma unroll
          for (int b2 = 0; b2 < 2; ++b2)
            acc[mm][a2][b2] += (double)aj.f[a2] * (double)ak.f[b2];
      }
    }
    const double wsc = isY ? 12.0 : 10.0;
    #pragma unroll
    for (int a2 = 0; a2 < 2; ++a2) {
      #pragma unroll
      for (int b2 = 0; b2 < 2; ++b2) {
        const int j = j0 + a2, kk = k0 + b2;
        const double gdd = acc[2][a2][b2], gd = acc[1][a2][b2], g0 = acc[0][a2][b2];
        const double cs = 100.0 * (gdd + ((j == kk) ? 0.1 : 0.0));
        const double g  = gdd + gd + wsc * g0;
        G[j][kk] = g;
        C[j][kk] = (mid >= 2) ? (cs + g) : cs;
      }
    }
  }
  if (tid < 16) {
    const int j = tid;
    Ae[0][j] = (double)P  [0*16+j];
    Ae[1][j] = (double)Pd [0*16+j];
    Ae[2][j] = (double)Pdd[0*16+j];
    if (!isY) {
      Ae[3][j] = (double)Pd[127*16+j];
      for (int r = 4; r < 8; ++r) Ae[r][j] = (j == r) ? 1.0 : 0.0;
    } else {
      Ae[3][j] = (double)P [127*16+j];
      Ae[4][j] = (double)Pd[127*16+j];
      for (int r = 5; r < 9; ++r) Ae[r][j] = (j == (r-1)) ? 1.0 : 0.0;
    }
  }
  __syncthreads();

  for (int e = tid; e < n * w; e += 64) {
    const int r = e / w, c = e % w;
    double val;
    if (c < n) {
      if (r < 16) val = (c < 16) ? C[r][c] : Ae[c-16][r];
      else        val = (c < 16) ? Ae[r-16][c] : 0.0;
    } else {
      val = ((c - n) == r) ? 1.0 : 0.0;
    }
    aug[r][c] = val;
  }
  __syncthreads();

  // Gauss-Jordan with partial pivoting (wave-parallel)
  const int hw  = (w + 1) >> 1;       // half-row width
  const int rw  = tid >> 1;           // row handled by this lane (2 lanes/row)
  const int hf  = tid & 1;
  for (int kk = 0; kk < n; ++kk) {
    // parallel argmax pivot over rows kk..n-1 (smallest index on ties)
    {
      double a = (tid >= kk && tid < n) ? fabs(aug[tid][kk]) : -1.0;
      int p = tid;
      #pragma unroll
      for (int off = 1; off < 64; off <<= 1) {
        const double oa = __shfl_xor(a, off);
        const int    op = __shfl_xor(p, off);
        if (oa > a || (oa == a && op < p)) { a = oa; p = op; }
      }
      if (tid == 0) pivs = p;
    }
    __syncthreads();
    const int p = pivs;
    if (p != kk) {
      for (int c = tid; c < w; c += 64) { double t = aug[kk][c]; aug[kk][c] = aug[p][c]; aug[p][c] = t; }
    }
    __syncthreads();
    const double ipiv = 1.0 / aug[kk][kk];
    for (int c = tid; c < w; c += 64) aug[kk][c] *= ipiv;
    if (tid < n) fcol[tid] = aug[tid][kk];   // fcol[kk] races with scale but is unused
    __syncthreads();
    if (rw < n && rw != kk) {
      const double f = fcol[rw];
      const int c0 = hf * hw;
      const int c1 = (c0 + hw < w) ? (c0 + hw) : w;
      for (int c = c0; c < c1; ++c) aug[rw][c] -= f * aug[kk][c];
    }
    __syncthreads();
  }

  if (mid == 0) {
    for (int e = tid; e < 16*8; e += 64) ws[WS_NX0 + e] = (float)aug[e >> 3][n + 16 + (e & 7)];
  } else if (mid == 1) {
    for (int e = tid; e < 16*9; e += 64) ws[WS_NY0 + e] = (float)aug[e / 9][n + 16 + (e % 9)];
  } else if (mid == 2) {
    for (int e = tid; e < 256;  e += 64) ws[WS_MX + e] = (float)aug[e >> 4][n + (e & 15)];
    for (int e = tid; e < 16*8; e += 64) ws[WS_NX + e] = (float)aug[e >> 3][n + 16 + (e & 7)];
  } else {
    for (int e = tid; e < 256;  e += 64) ws[WS_MY + e] = (float)aug[e >> 4][n + (e & 15)];
    for (int e = tid; e < 16*9; e += 64) ws[WS_NY + e] = (float)aug[e / 9][n + 16 + (e % 9)];
  }

  if (mid >= 2) {
    for (int e = tid; e < 256; e += 64) {
      const int j = e >> 4, kk = e & 15;
      double s = 0.0;
      for (int mm = 0; mm < 16; ++mm) s += aug[j][n + mm] * G[mm][kk];
      ws[(mid == 2 ? WS_MGX : WS_MGY) + e] = (float)s;
    }
  }
}

// ---- main kernel: ONE wave (64 threads) per problem, 2 timesteps/thread ----
// Obstacle t0 trajectories in registers (20 VGPR), t1 in LDS: cuts DS-ops/iter.
__global__ __launch_bounds__(64) void planner_main(
    const float* __restrict__ P, const float* __restrict__ Pd, const float* __restrict__ Pdd,
    const float* __restrict__ init_state, const float* __restrict__ fin_state,
    const float* __restrict__ cobs, const float* __restrict__ vobs,
    const float* __restrict__ yub_g, const float* __restrict__ ylb_g,
    const float* __restrict__ lamx_g, const float* __restrict__ lamy_g,
    const float* __restrict__ cxp_g, const float* __restrict__ cyp_g,
    const float* __restrict__ ws, float* __restrict__ out)
{
  const int b    = blockIdx.x;
  const int tid  = threadIdx.x;        // timesteps t0 = tid, t1 = tid + 64
  const int o32  = tid & 31;           // reduction row owned (dup over cc)
  const int cc   = tid >> 5;
  const int rr   = tid & 15;           // solve row
  const int side = (tid >> 4) & 1;     // 0 = x-side, 1 = y-side
  const int q4   = tid >> 2;           // quad index (0..15)
  const int k    = tid & 3;            // lane-in-quad

  __shared__ alignas(16) float red[16*RS];      // [quad][o], 2.3 KB
  __shared__ alignas(16) float obsL1[5*64*4];   // 5.1 KB: t1 traj {x0,x1,y0,y1}
  __shared__ alignas(16) float cL[32];
  __shared__ alignas(16) float hL[32];

  // basis rows for both timesteps (j-pair packed) -- 96 VGPRs, the main state
  f32x2 Pr2[2][8], Pdr2[2][8], Pddr2[2][8];
  #pragma unroll
  for (int u = 0; u < 2; ++u) {
    const int t = tid + 64*u;
    #pragma unroll
    for (int q = 0; q < 4; ++q) {
      F4 a, bb, ce;
      a.v  = *reinterpret_cast<const float4*>(P   + t*16 + 4*q);
      bb.v = *reinterpret_cast<const float4*>(Pd  + t*16 + 4*q);
      ce.v = *reinterpret_cast<const float4*>(Pdd + t*16 + 4*q);
      Pr2  [u][2*q+0] = f32x2{a.f[0],  a.f[1]};  Pr2  [u][2*q+1] = f32x2{a.f[2],  a.f[3]};
      Pdr2 [u][2*q+0] = f32x2{bb.f[0], bb.f[1]}; Pdr2 [u][2*q+1] = f32x2{bb.f[2], bb.f[3]};
      Pddr2[u][2*q+0] = f32x2{ce.f[0], ce.f[1]}; Pddr2[u][2*q+1] = f32x2{ce.f[2], ce.f[3]};
    }
  }

  // pre-scaled obstacle trajectories: t0 in registers, t1 into LDS
  f32x2 xot0r[5], yot0r[5];
  {
    const float tt0 = (float)tid        * (10.0f/127.0f);
    const float tt1 = (float)(tid + 64) * (10.0f/127.0f);
    #pragma unroll
    for (int o5 = 0; o5 < 5; ++o5) {
      const int o = 2*o5;
      const float xo0 = cobs[b*20+o],    xo1 = cobs[b*20+o+1];
      const float yo0 = cobs[b*20+10+o], yo1 = cobs[b*20+11+o];
      const float vx0 = vobs[b*20+o],    vx1 = vobs[b*20+o+1];
      const float vy0 = vobs[b*20+10+o], vy1 = vobs[b*20+11+o];
      xot0r[o5] = f32x2{3.2f*fmaf(vx0,tt0,xo0), 3.2f*fmaf(vx1,tt0,xo1)};
      yot0r[o5] = f32x2{6.0f*fmaf(vy0,tt0,yo0), 6.0f*fmaf(vy1,tt0,yo1)};
      *reinterpret_cast<float4*>(&obsL1[o5*256 + tid*4]) =
          float4{3.2f*fmaf(vx0,tt1,xo1*0.f+xo0), 3.2f*fmaf(vx1,tt1,xo1),
                 6.0f*fmaf(vy0,tt1,yo0),         6.0f*fmaf(vy1,tt1,yo1)};
    }
  }
  const float yub = yub_g[b], ylb = ylb_g[b];

  // lambda carry for owned reduction row (dup across cc)
  float lam = (o32 < 16) ? lamx_g[b*16 + o32] : lamy_g[b*16 + (o32 - 16)];

  // per-lane solve-row setup: const term, initial c (row rr, side)
  float constv, myc;
  {
    float beq[9];
    const float vi  = init_state[b*4+2];
    const float psi = init_state[b*4+3];
    if (side == 0) {
      beq[0] = init_state[b*4+0];
      beq[1] = vi * cosf(psi);
      beq[2] = 0.f;
      beq[3] = fin_state[b*3+0];
      #pragma unroll
      for (int i2 = 0; i2 < 4; ++i2) beq[4+i2] = cxp_g[b*4+i2];
      beq[8] = 0.f;                      // pad: multiplies in-bounds junk * 0
    } else {
      beq[0] = init_state[b*4+1];
      beq[1] = vi * sinf(psi);
      beq[2] = 0.f;
      beq[3] = fin_state[b*3+1];
      beq[4] = 0.f;
      #pragma unroll
      for (int i2 = 0; i2 < 4; ++i2) beq[5+i2] = cyp_g[b*4+i2];
    }
    const int nstr = side ? 9 : 8;
    const float* Np  = ws + (side ? WS_NY  : WS_NX ) + rr*nstr;
    const float* N0p = ws + (side ? WS_NY0 : WS_NX0) + rr*nstr;
    float cv = 0.f, c0 = 0.f;
    #pragma unroll
    for (int mm = 0; mm < 9; ++mm) {
      const float bm = beq[mm];
      cv = fmaf(Np[mm],  bm, cv);
      c0 = fmaf(N0p[mm], bm, c0);
    }
    constv = cv;
    myc    = c0;
  }
  if (tid < 32) cL[tid] = myc;           // same-wave DS ordering

  const float* Mrow  = ws + (side ? WS_MY  : WS_MX ) + rr*16;
  const float* MGrow = ws + (side ? WS_MGY : WS_MGX) + rr*16;
  const bool  kb2 = (k & 2) != 0;
  const int   k1  = k & 1;

  #pragma unroll 1
  for (int it = 0; it < MAXIT; ++it) {
    __builtin_amdgcn_wave_barrier();
    // ---- forward matvecs, t0 then t1 (6 packed accumulators reused) ----
    float x0,y0,xd0,yd0,xdd0,ydd0, x1,y1,xd1,yd1,xdd1,ydd1;
    #pragma unroll
    for (int u = 0; u < 2; ++u) {
      f32x2 xv{},yv{},xdv{},ydv{},xddv{},yddv{};
      #pragma unroll
      for (int q = 0; q < 4; ++q) {
        F4 cx4, cy4;
        cx4.v = *reinterpret_cast<const float4*>(&cL[4*q]);
        cy4.v = *reinterpret_cast<const float4*>(&cL[16 + 4*q]);
        const f32x2 c01 = f32x2{cx4.f[0], cx4.f[1]}, c23 = f32x2{cx4.f[2], cx4.f[3]};
        const f32x2 d01 = f32x2{cy4.f[0], cy4.f[1]}, d23 = f32x2{cy4.f[2], cy4.f[3]};
        xv   = pfma(Pr2  [u][2*q], c01, xv);   xv   = pfma(Pr2  [u][2*q+1], c23, xv);
        yv   = pfma(Pr2  [u][2*q], d01, yv);   yv   = pfma(Pr2  [u][2*q+1], d23, yv);
        xdv  = pfma(Pdr2 [u][2*q], c01, xdv);  xdv  = pfma(Pdr2 [u][2*q+1], c23, xdv);
        ydv  = pfma(Pdr2 [u][2*q], d01, ydv);  ydv  = pfma(Pdr2 [u][2*q+1], d23, ydv);
        xddv = pfma(Pddr2[u][2*q], c01, xddv); xddv = pfma(Pddr2[u][2*q+1], c23, xddv);
        yddv = pfma(Pddr2[u][2*q], d01, yddv); yddv = pfma(Pddr2[u][2*q+1], d23, yddv);
      }
      if (u == 0) {
        x0=xv.x+xv.y; y0=yv.x+yv.y; xd0=xdv.x+xdv.y; yd0=ydv.x+ydv.y;
        xdd0=xddv.x+xddv.y; ydd0=yddv.x+yddv.y;
      } else {
        x1=xv.x+xv.y; y1=yv.x+yv.y; xd1=xdv.x+xdv.y; yd1=ydv.x+ydv.y;
        xdd1=xddv.x+xddv.y; ydd1=yddv.x+yddv.y;
      }
    }

    // ---- projections ----
    const float ria0 = rsqrtf(fmaxf(fmaf(xdd0,xdd0,ydd0*ydd0), 1e-36f));
    const float ga10 = 1.0f - fminf(1.0f, 18.0f*ria0);
    const float riv0 = rsqrtf(fmaxf(fmaf(xd0,xd0,yd0*yd0), 1e-36f));
    const float gv10 = 1.0f - fminf(fmaxf(1.0f, 0.1f*riv0), 30.0f*riv0);
    const float ria1 = rsqrtf(fmaxf(fmaf(xdd1,xdd1,ydd1*ydd1), 1e-36f));
    const float ga11 = 1.0f - fminf(1.0f, 18.0f*ria1);
    const float riv1 = rsqrtf(fmaxf(fmaf(xd1,xd1,yd1*yd1), 1e-36f));
    const float gv11 = 1.0f - fminf(fmaxf(1.0f, 0.1f*riv1), 30.0f*riv1);

    // ---- obstacles: t0 from registers, t1 from LDS ----
    f32x2 Sx0{}, Sy0{}, Sx1{}, Sy1{};
    {
      const f32x2 xb0 = f32x2{3.2f*x0, 3.2f*x0}, yb0 = f32x2{6.0f*y0, 6.0f*y0};
      const f32x2 xb1 = f32x2{3.2f*x1, 3.2f*x1}, yb1 = f32x2{6.0f*y1, 6.0f*y1};
      #pragma unroll
      for (int o5 = 0; o5 < 5; ++o5) {
        F4 ob1;
        ob1.v = *reinterpret_cast<const float4*>(&obsL1[o5*256 + tid*4]);
        const f32x2 bw0 = xb0 - xot0r[o5];
        const f32x2 aw0 = yb0 - yot0r[o5];
        const f32x2 bw1 = xb1 - f32x2{ob1.f[0], ob1.f[1]};
        const f32x2 aw1 = yb1 - f32x2{ob1.f[2], ob1.f[3]};
        const f32x2 r20 = pfma(bw0,bw0,aw0*aw0);
        const f32x2 r21 = pfma(bw1,bw1,aw1*aw1);
        const f32x2 ee0 = f32x2{
          fmaxf(fmaf(19.2f, rsqrtf(fmaxf(r20.x,1e-36f)), -1.0f), 0.f),
          fmaxf(fmaf(19.2f, rsqrtf(fmaxf(r20.y,1e-36f)), -1.0f), 0.f)};
        const f32x2 ee1 = f32x2{
          fmaxf(fmaf(19.2f, rsqrtf(fmaxf(r21.x,1e-36f)), -1.0f), 0.f),
          fmaxf(fmaf(19.2f, rsqrtf(fmaxf(r21.y,1e-36f)), -1.0f), 0.f)};
        Sx0 = pfma(ee0, bw0, Sx0);  Sy0 = pfma(ee0, aw0, Sy0);
        Sx1 = pfma(ee1, bw1, Sx1);  Sy1 = pfma(ee1, aw1, Sy1);
      }
    }
    const float c0p0 = -(Sx0.x+Sx0.y)*0.3125f;
    const float rln0 = fmaxf(y0-yub,0.f) - fmaxf(ylb-y0,0.f);
    const float c2p0 = rln0 - (Sy0.x+Sy0.y)*(1.0f/6.0f);
    const float c0dd0 = xdd0*ga10, c0d0 = xd0*gv10;
    const float c2dd0 = ydd0*ga10, c2d0 = yd0*gv10;
    const float c0p1 = -(Sx1.x+Sx1.y)*0.3125f;
    const float rln1 = fmaxf(y1-yub,0.f) - fmaxf(ylb-y1,0.f);
    const float c2p1 = rln1 - (Sy1.x+Sy1.y)*(1.0f/6.0f);
    const float c0dd1 = xdd1*ga11, c0d1 = xd1*gv11;
    const float c2dd1 = ydd1*ga11, c2d1 = yd1*gv11;

    // ---- back-projection (pre-summed over own 2 t's) + quad DPP reduce ----
    float outv[8];
    #pragma unroll
    for (int s2 = 0; s2 < 8; ++s2) outv[s2] = 0.f;
    {
      const f32x2 A00{c0dd0,c0dd0}, D00{c0d0,c0d0}, Q00{c0p0,c0p0};
      const f32x2 A20{c2dd0,c2dd0}, D20{c2d0,c2d0}, Q20{c2p0,c2p0};
      const f32x2 A01{c0dd1,c0dd1}, D01{c0d1,c0d1}, Q01{c0p1,c0p1};
      const f32x2 A21{c2dd1,c2dd1}, D21{c2d1,c2d1}, Q21{c2p1,c2p1};
      #pragma unroll
      for (int j2 = 0; j2 < 8; ++j2) {
        f32x2 vx = pfma(A00, Pddr2[0][j2], pfma(D00, Pdr2[0][j2], Q00*Pr2[0][j2]));
        vx = pfma(A01, Pddr2[1][j2], pfma(D01, Pdr2[1][j2], pfma(Q01, Pr2[1][j2], vx)));
        f32x2 vy = pfma(A20, Pddr2[0][j2], pfma(D20, Pdr2[0][j2], Q20*Pr2[0][j2]));
        vy = pfma(A21, Pddr2[1][j2], pfma(D21, Pdr2[1][j2], pfma(Q21, Pr2[1][j2], vy)));
        // quad sums (each covers 8 timesteps)
        const float qx0 = qsum(vx.x), qx1 = qsum(vx.y);
        const float qy0 = qsum(vy.x), qy1 = qsum(vy.y);
        // lane k of each quad keeps o-chunk [8k, 8k+8)
        const float s0 = kb2 ? qy0 : qx0;
        const float s1 = kb2 ? qy1 : qx1;
        const bool match = (k1 == (j2 >> 2));
        const int  sb = 2*(j2 & 3);
        outv[sb]   = match ? s0 : outv[sb];
        outv[sb+1] = match ? s1 : outv[sb+1];
      }
    }
    __builtin_amdgcn_wave_barrier();
    {
      float* wr = red + q4*RS + 8*k;
      *reinterpret_cast<float4*>(wr)     = float4{outv[0],outv[1],outv[2],outv[3]};
      *reinterpret_cast<float4*>(wr + 4) = float4{outv[4],outv[5],outv[6],outv[7]};
    }
    __builtin_amdgcn_wave_barrier();

    // ---- reduce 16 quad-rows for owned column o32 ----
    float h;
    {
      const float* rd = red + (cc*8)*RS + o32;
      float s = 0.f;
      #pragma unroll
      for (int i = 0; i < 8; ++i) s += rd[i*RS];
      s += __shfl_xor(s, 32);
      lam -= s;
      h = lam - s;                         // lam_old - 2S
    }
    __builtin_amdgcn_wave_barrier();
    if (tid < 32) hL[tid] = h;
    __builtin_amdgcn_wave_barrier();

    // ---- fused solve: c' = MG*c + M*h + const ----
    {
      f32x2 accv{};
      #pragma unroll
      for (int q = 0; q < 4; ++q) {
        F4 m4, g4, h4, c4;
        m4.v = *reinterpret_cast<const float4*>(Mrow  + 4*q);
        g4.v = *reinterpret_cast<const float4*>(MGrow + 4*q);
        h4.v = *reinterpret_cast<const float4*>(&hL[side*16 + 4*q]);
        c4.v = *reinterpret_cast<const float4*>(&cL[side*16 + 4*q]);
        accv = pfma(f32x2{m4.f[0],m4.f[1]}, f32x2{h4.f[0],h4.f[1]}, accv);
        accv = pfma(f32x2{g4.f[0],g4.f[1]}, f32x2{c4.f[0],c4.f[1]}, accv);
        accv = pfma(f32x2{m4.f[2],m4.f[3]}, f32x2{h4.f[2],h4.f[3]}, accv);
        accv = pfma(f32x2{g4.f[2],g4.f[3]}, f32x2{c4.f[2],c4.f[3]}, accv);
      }
      myc = constv + accv.x + accv.y;
    }
    __builtin_amdgcn_wave_barrier();
    if (tid < 32) cL[tid] = myc;           // next iter reads (same-wave order)
  }

  if (tid < 32) out[b*32 + tid] = myc;
}

extern "C" void kernel_launch(void* const* d_in, const int* in_sizes, int n_in,
                              void* d_out, int out_size, void* d_ws, size_t ws_size,
                              hipStream_t stream) {
  const float* P    = (const float*)d_in[0];
  const float* Pd   = (const float*)d_in[1];
  const float* Pdd  = (const float*)d_in[2];
  const float* init = (const float*)d_in[3];
  const float* fin  = (const float*)d_in[4];
  const float* cobs = (const float*)d_in[5];
  const float* vobs = (const float*)d_in[6];
  const float* yub  = (const float*)d_in[7];
  const float* ylb  = (const float*)d_in[8];
  const float* lamx = (const float*)d_in[9];
  const float* lamy = (const float*)d_in[10];
  const float* cxp  = (const float*)d_in[11];
  const float* cyp  = (const float*)d_in[12];
  float* ws  = (float*)d_ws;
  float* o   = (float*)d_out;

  planner_setup<<<dim3(4), dim3(64), 0, stream>>>(P, Pd, Pdd, ws);
  planner_main<<<dim3(NBATCH), dim3(64), 0, stream>>>(
      P, Pd, Pdd, init, fin, cobs, vobs, yub, ylb, lamx, lamy, cxp, cyp, ws, o);
}